// Round 1
// baseline (3077.517 us; speedup 1.0000x reference)
//
#include <hip/hip_runtime.h>
#include <math.h>

constexpr int D = 64;

__device__ __forceinline__ float wave_reduce_sum(float v) {
    #pragma unroll
    for (int m = 1; m < 64; m <<= 1)
        v += __shfl_xor(v, m, 64);
    return v;
}

// ---- L0: user embeddings = l2norm(user_w), wave per row ----
__global__ void k_user_norm(const float* __restrict__ user_w,
                            float* __restrict__ x, int U_) {
    int wid  = (blockIdx.x * blockDim.x + threadIdx.x) >> 6;
    int lane = threadIdx.x & 63;
    if (wid >= U_) return;
    size_t o = (size_t)wid * D + lane;
    float v  = user_w[o];
    float ss = wave_reduce_sum(v * v);
    float n  = sqrtf(ss);
    x[o] = v / fmaxf(n, 1e-12f);
}

// ---- L0: item embeddings = l2norm([audio, artist+album] @ W^T + b) ----
// Wave per item. W (64x128 row-major) staged transposed in LDS: Wt[k*64+d]
// so lanes (d) read 2-way-bank-aliased (free). feat broadcast via shfl.
__global__ void __launch_bounds__(256) k_item(
        const float* __restrict__ audio,
        const float* __restrict__ artist_w, const float* __restrict__ album_w,
        const float* __restrict__ proj_W,   const float* __restrict__ proj_b,
        const int* __restrict__ artist_ids, const int* __restrict__ album_ids,
        float* __restrict__ x, int I_, int U_) {
    __shared__ float Wt[128 * 64];   // 32 KiB
    for (int idx = threadIdx.x; idx < 128 * 64; idx += 256) {
        int d = idx >> 7, k = idx & 127;
        Wt[k * 64 + d] = proj_W[idx];     // one-time transpose load
    }
    __syncthreads();

    int lane = threadIdx.x & 63;
    int item = __builtin_amdgcn_readfirstlane(
                   (int)((blockIdx.x * blockDim.x + threadIdx.x) >> 6));
    if (item >= I_) return;              // wave-uniform, no barriers below

    int aid = artist_ids[item];
    int bid = album_ids[item];
    float fa = audio[(size_t)item * D + lane];
    float fm = artist_w[(size_t)aid * D + lane] + album_w[(size_t)bid * D + lane];

    float acc = proj_b[lane];
    #pragma unroll 8
    for (int k = 0; k < 64; ++k)
        acc = fmaf(__shfl(fa, k, 64), Wt[k * 64 + lane], acc);
    #pragma unroll 8
    for (int k = 0; k < 64; ++k)
        acc = fmaf(__shfl(fm, k, 64), Wt[(64 + k) * 64 + lane], acc);

    float ss = wave_reduce_sum(acc * acc);
    float n  = sqrtf(ss);
    x[(size_t)(U_ + item) * D + lane] = acc / fmaxf(n, 1e-12f);
}

// ---- weighted degree via atomics (self-loop +1 folded into k_dinv) ----
__global__ void k_degree(const float* __restrict__ ew,
                         const int* __restrict__ u_idx,
                         const int* __restrict__ i_idx,
                         float* __restrict__ deg, int E_, int U_) {
    int e = blockIdx.x * blockDim.x + threadIdx.x;
    if (e >= E_) return;
    float w = fmaxf(ew[e], 1e-6f);
    atomicAdd(&deg[u_idx[e]], w);
    atomicAdd(&deg[U_ + i_idx[e]], w);
}

__global__ void k_dinv(float* __restrict__ deg, int N_) {
    int n = blockIdx.x * blockDim.x + threadIdx.x;
    if (n >= N_) return;
    deg[n] = 1.0f / sqrtf(deg[n] + 1.0f);   // in place: deg -> dinv
}

// ---- fused: acc (+)= x_cur ; seed = dinv^2 * x_cur  (self-loop term) ----
__global__ void k_seed(const float* __restrict__ xcur,
                       const float* __restrict__ dinv,
                       float* __restrict__ acc, float* __restrict__ seed,
                       int N_, int first) {
    int idx = blockIdx.x * blockDim.x + threadIdx.x;   // float4 index
    if (idx >= N_ * 16) return;                        // N*64/4
    int n = idx >> 4;
    float di = dinv[n];
    float s  = di * di;
    float4 v = ((const float4*)xcur)[idx];
    float4 a;
    if (first) a = v;
    else {
        a = ((const float4*)acc)[idx];
        a.x += v.x; a.y += v.y; a.z += v.z; a.w += v.w;
    }
    ((float4*)acc)[idx] = a;
    ((float4*)seed)[idx] = make_float4(v.x * s, v.y * s, v.z * s, v.w * s);
}

// ---- one propagation layer: both edge directions, wave per edge ----
__global__ void k_edge(const float* __restrict__ xs, float* __restrict__ xn,
                       const float* __restrict__ dinv,
                       const float* __restrict__ ew,
                       const int* __restrict__ u_idx,
                       const int* __restrict__ i_idx, int E_, int U_) {
    int wid  = __builtin_amdgcn_readfirstlane(
                   (int)((blockIdx.x * blockDim.x + threadIdx.x) >> 6));
    int lane = threadIdx.x & 63;
    if (wid >= E_) return;
    int u = u_idx[wid];
    int v = U_ + i_idx[wid];
    float w   = fmaxf(ew[wid], 1e-6f);
    float nrm = dinv[u] * w * dinv[v];
    float xu = xs[(size_t)u * D + lane];
    float xv = xs[(size_t)v * D + lane];
    atomicAdd(&xn[(size_t)v * D + lane], nrm * xu);
    atomicAdd(&xn[(size_t)u * D + lane], nrm * xv);
}

// ---- epilogue: acc += x_last ; out = l2norm(acc/4), wave per row ----
__global__ void k_final(const float* __restrict__ xlast,
                        float* __restrict__ acc, int N_) {
    int wid  = (blockIdx.x * blockDim.x + threadIdx.x) >> 6;
    int lane = threadIdx.x & 63;
    if (wid >= N_) return;
    size_t o = (size_t)wid * D + lane;
    float v  = (acc[o] + xlast[o]) * 0.25f;
    float ss = wave_reduce_sum(v * v);
    float n  = sqrtf(ss);
    acc[o] = v / fmaxf(n, 1e-12f);
}

extern "C" void kernel_launch(void* const* d_in, const int* in_sizes, int n_in,
                              void* d_out, int out_size, void* d_ws, size_t ws_size,
                              hipStream_t stream) {
    const float* user_w     = (const float*)d_in[0];
    const float* audio      = (const float*)d_in[1];
    const float* artist_w   = (const float*)d_in[2];
    const float* album_w    = (const float*)d_in[3];
    const float* proj_W     = (const float*)d_in[4];
    const float* proj_b     = (const float*)d_in[5];
    const float* ew         = (const float*)d_in[6];
    const int*   u_idx      = (const int*)d_in[7];
    const int*   i_idx      = (const int*)d_in[8];
    const int*   artist_ids = (const int*)d_in[9];
    const int*   album_ids  = (const int*)d_in[10];

    const int U_ = in_sizes[0] / D;
    const int I_ = in_sizes[1] / D;
    const int E_ = in_sizes[6];
    const int N_ = U_ + I_;

    float* acc = (float*)d_out;                 // acc lives in d_out
    char*  w   = (char*)d_ws;
    size_t xbytes = (size_t)N_ * D * sizeof(float);
    float* xA  = (float*)w;  w += xbytes;
    float* xB  = (float*)w;  w += xbytes;
    float* deg = (float*)w;                     // N floats, becomes dinv

    hipMemsetAsync(deg, 0, (size_t)N_ * sizeof(float), stream);

    // L0 embeddings -> xA
    k_user_norm<<<(U_ + 3) / 4, 256, 0, stream>>>(user_w, xA, U_);
    k_item<<<(I_ + 3) / 4, 256, 0, stream>>>(audio, artist_w, album_w, proj_W,
                                             proj_b, artist_ids, album_ids,
                                             xA, I_, U_);

    // gcn_norm
    k_degree<<<(E_ + 255) / 256, 256, 0, stream>>>(ew, u_idx, i_idx, deg, E_, U_);
    k_dinv<<<(N_ + 255) / 256, 256, 0, stream>>>(deg, N_);

    const int seed_grid = (N_ * 16 + 255) / 256;
    const int edge_grid = (E_ + 3) / 4;

    // layer 1: acc = x0, xB = selfloop-seed; xB += cross terms
    k_seed<<<seed_grid, 256, 0, stream>>>(xA, deg, acc, xB, N_, 1);
    k_edge<<<edge_grid, 256, 0, stream>>>(xA, xB, deg, ew, u_idx, i_idx, E_, U_);
    // layer 2
    k_seed<<<seed_grid, 256, 0, stream>>>(xB, deg, acc, xA, N_, 0);
    k_edge<<<edge_grid, 256, 0, stream>>>(xB, xA, deg, ew, u_idx, i_idx, E_, U_);
    // layer 3
    k_seed<<<seed_grid, 256, 0, stream>>>(xA, deg, acc, xB, N_, 0);
    k_edge<<<edge_grid, 256, 0, stream>>>(xA, xB, deg, ew, u_idx, i_idx, E_, U_);

    // epilogue
    k_final<<<(N_ + 3) / 4, 256, 0, stream>>>(xB, acc, N_);
}

// Round 2
// 1685.766 us; speedup vs baseline: 1.8256x; 1.8256x over previous
//
#include <hip/hip_runtime.h>
#include <math.h>

constexpr int D = 64;

__device__ __forceinline__ float wave_reduce_sum(float v) {
    #pragma unroll
    for (int m = 1; m < 64; m <<= 1)
        v += __shfl_xor(v, m, 64);
    return v;
}

// ---- L0: user embeddings = l2norm(user_w), wave per row ----
__global__ void k_user_norm(const float* __restrict__ user_w,
                            float* __restrict__ x, int U_) {
    int wid  = (blockIdx.x * blockDim.x + threadIdx.x) >> 6;
    int lane = threadIdx.x & 63;
    if (wid >= U_) return;
    size_t o = (size_t)wid * D + lane;
    float v  = user_w[o];
    float ss = wave_reduce_sum(v * v);
    float n  = sqrtf(ss);
    x[o] = v / fmaxf(n, 1e-12f);
}

// ---- L0: item embeddings = l2norm([audio, artist+album] @ W^T + b) ----
__global__ void __launch_bounds__(256) k_item(
        const float* __restrict__ audio,
        const float* __restrict__ artist_w, const float* __restrict__ album_w,
        const float* __restrict__ proj_W,   const float* __restrict__ proj_b,
        const int* __restrict__ artist_ids, const int* __restrict__ album_ids,
        float* __restrict__ x, int I_, int U_) {
    __shared__ float Wt[128 * 64];   // 32 KiB, transposed: Wt[k*64+d]
    for (int idx = threadIdx.x; idx < 128 * 64; idx += 256) {
        int d = idx >> 7, k = idx & 127;
        Wt[k * 64 + d] = proj_W[idx];
    }
    __syncthreads();

    int lane = threadIdx.x & 63;
    int item = __builtin_amdgcn_readfirstlane(
                   (int)((blockIdx.x * blockDim.x + threadIdx.x) >> 6));
    if (item >= I_) return;              // wave-uniform

    int aid = artist_ids[item];
    int bid = album_ids[item];
    float fa = audio[(size_t)item * D + lane];
    float fm = artist_w[(size_t)aid * D + lane] + album_w[(size_t)bid * D + lane];

    float acc = proj_b[lane];
    #pragma unroll 8
    for (int k = 0; k < 64; ++k)
        acc = fmaf(__shfl(fa, k, 64), Wt[k * 64 + lane], acc);
    #pragma unroll 8
    for (int k = 0; k < 64; ++k)
        acc = fmaf(__shfl(fm, k, 64), Wt[(64 + k) * 64 + lane], acc);

    float ss = wave_reduce_sum(acc * acc);
    float n  = sqrtf(ss);
    x[(size_t)(U_ + item) * D + lane] = acc / fmaxf(n, 1e-12f);
}

// ---- weighted degree + directed-entry counts (one pass) ----
__global__ void k_deg_cnt(const float* __restrict__ ew,
                          const int* __restrict__ u_idx,
                          const int* __restrict__ i_idx,
                          float* __restrict__ deg, int* __restrict__ cnt,
                          int E_, int U_) {
    int e = blockIdx.x * blockDim.x + threadIdx.x;
    if (e >= E_) return;
    float w = fmaxf(ew[e], 1e-6f);
    int u = u_idx[e], v = U_ + i_idx[e];
    atomicAdd(&deg[u], w);
    atomicAdd(&deg[v], w);
    atomicAdd(&cnt[u], 1);
    atomicAdd(&cnt[v], 1);
}

__global__ void k_dinv(float* __restrict__ deg, int N_) {
    int n = blockIdx.x * blockDim.x + threadIdx.x;
    if (n >= N_) return;
    deg[n] = 1.0f / sqrtf(deg[n] + 1.0f);   // +1 = self loop; in place
}

// ---- exclusive scan of cnt[N] -> rowptr[N+1] (3 kernels) ----
__global__ void k_scan1(const int* __restrict__ cnt, int* __restrict__ rowptr,
                        int* __restrict__ bsum, int N_) {
    __shared__ int tmp[1024];
    int tid = threadIdx.x;
    int gid = blockIdx.x * 1024 + tid;
    int v = (gid < N_) ? cnt[gid] : 0;
    tmp[tid] = v; __syncthreads();
    for (int off = 1; off < 1024; off <<= 1) {
        int t = (tid >= off) ? tmp[tid - off] : 0;
        __syncthreads();
        tmp[tid] += t;
        __syncthreads();
    }
    if (gid < N_) rowptr[gid] = tmp[tid] - v;   // block-local exclusive
    if (tid == 1023) bsum[blockIdx.x] = tmp[1023];
}

__global__ void k_scan2(const int* __restrict__ bsum, int* __restrict__ boff,
                        int nb) {
    __shared__ int tmp[256];
    int tid = threadIdx.x;
    int v = (tid < nb) ? bsum[tid] : 0;
    tmp[tid] = v; __syncthreads();
    for (int off = 1; off < 256; off <<= 1) {
        int t = (tid >= off) ? tmp[tid - off] : 0;
        __syncthreads();
        tmp[tid] += t;
        __syncthreads();
    }
    if (tid < nb) boff[tid] = tmp[tid] - v;
    if (tid == 0) boff[nb] = tmp[255];          // grand total
}

__global__ void k_scan3(int* __restrict__ rowptr, int* __restrict__ cursor,
                        const int* __restrict__ boff, int N_, int nb) {
    int gid = blockIdx.x * blockDim.x + threadIdx.x;
    if (gid < N_) {
        int r = rowptr[gid] + boff[gid >> 10];
        rowptr[gid] = r;
        cursor[gid] = r;
    } else if (gid == N_) {
        rowptr[N_] = boff[nb];
    }
}

// ---- fill CSR entries: (src, nrm) packed as int2 ----
__global__ void k_fill(const float* __restrict__ ew,
                       const int* __restrict__ u_idx,
                       const int* __restrict__ i_idx,
                       const float* __restrict__ dinv,
                       int* __restrict__ cursor, int2* __restrict__ ents,
                       int E_, int U_) {
    int e = blockIdx.x * blockDim.x + threadIdx.x;
    if (e >= E_) return;
    int u = u_idx[e], v = U_ + i_idx[e];
    float w = fmaxf(ew[e], 1e-6f);
    int nb = __float_as_int(dinv[u] * w * dinv[v]);
    int p = atomicAdd(&cursor[u], 1);
    ents[p] = make_int2(v, nb);
    p = atomicAdd(&cursor[v], 1);
    ents[p] = make_int2(u, nb);
}

// ---- one propagation layer, atomic-free pull; wave per destination row ----
// mode 0: first layer  -> xn = msg; acc = xold + msg
// mode 1: middle layer -> xn = msg; acc += msg
// mode 2: last layer   -> out = l2norm((acc + msg)/4)   (xn not written)
__global__ void k_gather(const float* __restrict__ xs, float* __restrict__ xn,
                         float* __restrict__ acc,
                         const float* __restrict__ dinv,
                         const int* __restrict__ rowptr,
                         const int2* __restrict__ ents,
                         int N_, int mode) {
    int wid = __builtin_amdgcn_readfirstlane(
                  (int)((blockIdx.x * blockDim.x + threadIdx.x) >> 6));
    int lane = threadIdx.x & 63;
    if (wid >= N_) return;
    size_t o = (size_t)wid * D + lane;
    float xold = xs[o];
    float di = dinv[wid];
    float a = di * di * xold;                 // self-loop term
    int beg = rowptr[wid], end = rowptr[wid + 1];
    for (int j0 = beg; j0 < end; j0 += 64) {
        int m = end - j0; if (m > 64) m = 64;
        int2 rec = make_int2(0, 0);
        if (lane < m) rec = ents[j0 + lane];  // coalesced edge-list read
        #pragma unroll 4
        for (int k = 0; k < m; ++k) {
            int   src = __shfl(rec.x, k, 64);
            float nm  = __int_as_float(__shfl(rec.y, k, 64));
            a = fmaf(nm, xs[(size_t)src * D + lane], a);  // 256 B coalesced
        }
    }
    if (mode == 2) {
        float v2 = (acc[o] + a) * 0.25f;
        float ss = wave_reduce_sum(v2 * v2);
        acc[o] = v2 / fmaxf(sqrtf(ss), 1e-12f);
    } else {
        xn[o] = a;
        acc[o] = (mode == 0) ? (xold + a) : (acc[o] + a);
    }
}

extern "C" void kernel_launch(void* const* d_in, const int* in_sizes, int n_in,
                              void* d_out, int out_size, void* d_ws, size_t ws_size,
                              hipStream_t stream) {
    const float* user_w     = (const float*)d_in[0];
    const float* audio      = (const float*)d_in[1];
    const float* artist_w   = (const float*)d_in[2];
    const float* album_w    = (const float*)d_in[3];
    const float* proj_W     = (const float*)d_in[4];
    const float* proj_b     = (const float*)d_in[5];
    const float* ew         = (const float*)d_in[6];
    const int*   u_idx      = (const int*)d_in[7];
    const int*   i_idx      = (const int*)d_in[8];
    const int*   artist_ids = (const int*)d_in[9];
    const int*   album_ids  = (const int*)d_in[10];

    const int U_ = in_sizes[0] / D;
    const int I_ = in_sizes[1] / D;
    const int E_ = in_sizes[6];
    const int N_ = U_ + I_;
    const int nb = (N_ + 1023) / 1024;          // scan blocks (147 <= 256)

    float* acc = (float*)d_out;
    char*  p   = (char*)d_ws;
    size_t xbytes = (size_t)N_ * D * sizeof(float);
    float* xA     = (float*)p;  p += xbytes;                    // 38.4 MB
    float* xB     = (float*)p;  p += xbytes;                    // 38.4 MB
    int2*  ents   = (int2*)p;   p += (size_t)2 * E_ * sizeof(int2); // 32 MB
    float* deg    = (float*)p;  p += (size_t)N_ * 4;            // becomes dinv
    int*   cnt    = (int*)p;    p += (size_t)N_ * 4;            // adjacent to deg
    int*   rowptr = (int*)p;    p += (size_t)(N_ + 1) * 4;
    int*   cursor = (int*)p;    p += (size_t)N_ * 4;
    int*   bsum   = (int*)p;    p += (size_t)nb * 4;
    int*   boff   = (int*)p;    p += (size_t)(nb + 1) * 4;

    // zero deg+cnt in one shot (adjacent)
    hipMemsetAsync(deg, 0, (size_t)N_ * 8, stream);

    // L0 embeddings -> xA
    k_user_norm<<<(U_ + 3) / 4, 256, 0, stream>>>(user_w, xA, U_);
    k_item<<<(I_ + 3) / 4, 256, 0, stream>>>(audio, artist_w, album_w, proj_W,
                                             proj_b, artist_ids, album_ids,
                                             xA, I_, U_);

    // degree + counts, dinv
    k_deg_cnt<<<(E_ + 255) / 256, 256, 0, stream>>>(ew, u_idx, i_idx, deg, cnt, E_, U_);
    k_dinv<<<(N_ + 255) / 256, 256, 0, stream>>>(deg, N_);

    // CSR build
    k_scan1<<<nb, 1024, 0, stream>>>(cnt, rowptr, bsum, N_);
    k_scan2<<<1, 256, 0, stream>>>(bsum, boff, nb);
    k_scan3<<<(N_ + 1 + 255) / 256, 256, 0, stream>>>(rowptr, cursor, boff, N_, nb);
    k_fill<<<(E_ + 255) / 256, 256, 0, stream>>>(ew, u_idx, i_idx, deg, cursor,
                                                 ents, E_, U_);

    // 3 layers, fused self-loop + running acc + epilogue
    const int ggrid = (N_ + 3) / 4;
    k_gather<<<ggrid, 256, 0, stream>>>(xA, xB, acc, deg, rowptr, ents, N_, 0);
    k_gather<<<ggrid, 256, 0, stream>>>(xB, xA, acc, deg, rowptr, ents, N_, 1);
    k_gather<<<ggrid, 256, 0, stream>>>(xA, xB, acc, deg, rowptr, ents, N_, 2);
}

// Round 3
// 1478.111 us; speedup vs baseline: 2.0821x; 1.1405x over previous
//
#include <hip/hip_runtime.h>
#include <hip/hip_fp16.h>
#include <math.h>

constexpr int D = 64;

__device__ __forceinline__ float wave_reduce_sum(float v) {
    #pragma unroll
    for (int m = 1; m < 64; m <<= 1)
        v += __shfl_xor(v, m, 64);
    return v;
}

// ---- L0: user embeddings = l2norm(user_w), wave per row; x stored fp16 ----
__global__ void k_user_norm(const float* __restrict__ user_w,
                            __half* __restrict__ x, int U_) {
    int wid  = (blockIdx.x * blockDim.x + threadIdx.x) >> 6;
    int lane = threadIdx.x & 63;
    if (wid >= U_) return;
    size_t o = (size_t)wid * D + lane;
    float v  = user_w[o];
    float ss = wave_reduce_sum(v * v);
    float n  = sqrtf(ss);
    x[o] = __float2half(v / fmaxf(n, 1e-12f));
}

// ---- L0: item embeddings = l2norm([audio, artist+album] @ W^T + b) ----
__global__ void __launch_bounds__(256) k_item(
        const float* __restrict__ audio,
        const float* __restrict__ artist_w, const float* __restrict__ album_w,
        const float* __restrict__ proj_W,   const float* __restrict__ proj_b,
        const int* __restrict__ artist_ids, const int* __restrict__ album_ids,
        __half* __restrict__ x, int I_, int U_) {
    __shared__ float Wt[128 * 64];   // 32 KiB, transposed: Wt[k*64+d]
    for (int idx = threadIdx.x; idx < 128 * 64; idx += 256) {
        int d = idx >> 7, k = idx & 127;
        Wt[k * 64 + d] = proj_W[idx];
    }
    __syncthreads();

    int lane = threadIdx.x & 63;
    int item = __builtin_amdgcn_readfirstlane(
                   (int)((blockIdx.x * blockDim.x + threadIdx.x) >> 6));
    if (item >= I_) return;              // wave-uniform

    int aid = artist_ids[item];
    int bid = album_ids[item];
    float fa = audio[(size_t)item * D + lane];
    float fm = artist_w[(size_t)aid * D + lane] + album_w[(size_t)bid * D + lane];

    float acc = proj_b[lane];
    #pragma unroll 8
    for (int k = 0; k < 64; ++k)
        acc = fmaf(__shfl(fa, k, 64), Wt[k * 64 + lane], acc);
    #pragma unroll 8
    for (int k = 0; k < 64; ++k)
        acc = fmaf(__shfl(fm, k, 64), Wt[(64 + k) * 64 + lane], acc);

    float ss = wave_reduce_sum(acc * acc);
    float n  = sqrtf(ss);
    x[(size_t)(U_ + item) * D + lane] = __float2half(acc / fmaxf(n, 1e-12f));
}

// ---- packed degree+count: one u64 atomic per endpoint ----
// packed += (1<<44) | (u64)(w * 2^32).  count = hi 20 bits, wsum = lo 44 bits.
// max degree here ~100 << 4096, so 44-bit weight field cannot overflow.
__global__ void k_deg_packed(const float* __restrict__ ew,
                             const int* __restrict__ u_idx,
                             const int* __restrict__ i_idx,
                             unsigned long long* __restrict__ packed,
                             int E_, int U_) {
    int e = blockIdx.x * blockDim.x + threadIdx.x;
    if (e >= E_) return;
    float w = fmaxf(ew[e], 1e-6f);
    unsigned long long inc = (1ULL << 44) |
                             (unsigned long long)(w * 4294967296.0f);
    atomicAdd(&packed[u_idx[e]], inc);
    atomicAdd(&packed[U_ + i_idx[e]], inc);
}

// ---- unpack: dinv = rsqrt(wsum + 1), cnt for the scan ----
__global__ void k_unpack(const unsigned long long* __restrict__ packed,
                         float* __restrict__ dinv, int* __restrict__ cnt,
                         int N_) {
    int n = blockIdx.x * blockDim.x + threadIdx.x;
    if (n >= N_) return;
    unsigned long long p = packed[n];
    cnt[n] = (int)(p >> 44);
    float wsum = (float)((double)(p & 0xFFFFFFFFFFFULL) * (1.0 / 4294967296.0));
    dinv[n] = 1.0f / sqrtf(wsum + 1.0f);    // +1 = self loop
}

// ---- exclusive scan of cnt[N] -> rowptr[N+1] (3 kernels) ----
__global__ void k_scan1(const int* __restrict__ cnt, int* __restrict__ rowptr,
                        int* __restrict__ bsum, int N_) {
    __shared__ int tmp[1024];
    int tid = threadIdx.x;
    int gid = blockIdx.x * 1024 + tid;
    int v = (gid < N_) ? cnt[gid] : 0;
    tmp[tid] = v; __syncthreads();
    for (int off = 1; off < 1024; off <<= 1) {
        int t = (tid >= off) ? tmp[tid - off] : 0;
        __syncthreads();
        tmp[tid] += t;
        __syncthreads();
    }
    if (gid < N_) rowptr[gid] = tmp[tid] - v;   // block-local exclusive
    if (tid == 1023) bsum[blockIdx.x] = tmp[1023];
}

__global__ void k_scan2(const int* __restrict__ bsum, int* __restrict__ boff,
                        int nb) {
    __shared__ int tmp[256];
    int tid = threadIdx.x;
    int v = (tid < nb) ? bsum[tid] : 0;
    tmp[tid] = v; __syncthreads();
    for (int off = 1; off < 256; off <<= 1) {
        int t = (tid >= off) ? tmp[tid - off] : 0;
        __syncthreads();
        tmp[tid] += t;
        __syncthreads();
    }
    if (tid < nb) boff[tid] = tmp[tid] - v;
    if (tid == 0) boff[nb] = tmp[255];          // grand total
}

__global__ void k_scan3(int* __restrict__ rowptr, int* __restrict__ cursor,
                        const int* __restrict__ boff, int N_, int nb) {
    int gid = blockIdx.x * blockDim.x + threadIdx.x;
    if (gid < N_) {
        int r = rowptr[gid] + boff[gid >> 10];
        rowptr[gid] = r;
        cursor[gid] = r;
    } else if (gid == N_) {
        rowptr[N_] = boff[nb];
    }
}

// ---- fill CSR entries: (src, nrm) packed as int2 ----
__global__ void k_fill(const float* __restrict__ ew,
                       const int* __restrict__ u_idx,
                       const int* __restrict__ i_idx,
                       const float* __restrict__ dinv,
                       int* __restrict__ cursor, int2* __restrict__ ents,
                       int E_, int U_) {
    int e = blockIdx.x * blockDim.x + threadIdx.x;
    if (e >= E_) return;
    int u = u_idx[e], v = U_ + i_idx[e];
    float w = fmaxf(ew[e], 1e-6f);
    int nb = __float_as_int(dinv[u] * w * dinv[v]);
    int p = atomicAdd(&cursor[u], 1);
    ents[p] = make_int2(v, nb);
    p = atomicAdd(&cursor[v], 1);
    ents[p] = make_int2(u, nb);
}

// ---- one propagation layer, atomic-free pull; wave per destination row ----
// x stored fp16, accumulation in f32, acc buffer f32 (= d_out).
// mode 0: first layer  -> xn = msg; acc = xold + msg
// mode 1: middle layer -> xn = msg; acc += msg
// mode 2: last layer   -> acc = l2norm((acc + msg)/4)   (xn not written)
__global__ void k_gather(const __half* __restrict__ xs, __half* __restrict__ xn,
                         float* __restrict__ acc,
                         const float* __restrict__ dinv,
                         const int* __restrict__ rowptr,
                         const int2* __restrict__ ents,
                         int N_, int mode) {
    int wid = __builtin_amdgcn_readfirstlane(
                  (int)((blockIdx.x * blockDim.x + threadIdx.x) >> 6));
    int lane = threadIdx.x & 63;
    if (wid >= N_) return;
    size_t o = (size_t)wid * D + lane;
    float xold = __half2float(xs[o]);
    float di = dinv[wid];
    float a = di * di * xold;                 // self-loop term
    int beg = rowptr[wid], end = rowptr[wid + 1];
    for (int j0 = beg; j0 < end; j0 += 64) {
        int m = end - j0; if (m > 64) m = 64;
        int2 rec = make_int2(0, 0);
        if (lane < m) rec = ents[j0 + lane];  // coalesced edge-list read
        #pragma unroll 4
        for (int k = 0; k < m; ++k) {
            int   src = __shfl(rec.x, k, 64);
            float nm  = __int_as_float(__shfl(rec.y, k, 64));
            a = fmaf(nm, __half2float(xs[(size_t)src * D + lane]), a);
        }
    }
    if (mode == 2) {
        float v2 = (acc[o] + a) * 0.25f;
        float ss = wave_reduce_sum(v2 * v2);
        acc[o] = v2 / fmaxf(sqrtf(ss), 1e-12f);
    } else {
        xn[o] = __float2half(a);
        acc[o] = (mode == 0) ? (xold + a) : (acc[o] + a);
    }
}

extern "C" void kernel_launch(void* const* d_in, const int* in_sizes, int n_in,
                              void* d_out, int out_size, void* d_ws, size_t ws_size,
                              hipStream_t stream) {
    const float* user_w     = (const float*)d_in[0];
    const float* audio      = (const float*)d_in[1];
    const float* artist_w   = (const float*)d_in[2];
    const float* album_w    = (const float*)d_in[3];
    const float* proj_W     = (const float*)d_in[4];
    const float* proj_b     = (const float*)d_in[5];
    const float* ew         = (const float*)d_in[6];
    const int*   u_idx      = (const int*)d_in[7];
    const int*   i_idx      = (const int*)d_in[8];
    const int*   artist_ids = (const int*)d_in[9];
    const int*   album_ids  = (const int*)d_in[10];

    const int U_ = in_sizes[0] / D;
    const int I_ = in_sizes[1] / D;
    const int E_ = in_sizes[6];
    const int N_ = U_ + I_;
    const int nb = (N_ + 1023) / 1024;          // scan blocks (147 <= 256)

    float* acc = (float*)d_out;
    char*  p   = (char*)d_ws;
    size_t xbytes = (size_t)N_ * D * sizeof(__half);
    __half* xA    = (__half*)p; p += xbytes;                        // 19.2 MB
    __half* xB    = (__half*)p; p += xbytes;                        // 19.2 MB
    int2*  ents   = (int2*)p;   p += (size_t)2 * E_ * sizeof(int2); // 32 MB
    unsigned long long* packed = (unsigned long long*)p; p += (size_t)N_ * 8;
    float* dinv   = (float*)p;  p += (size_t)N_ * 4;
    int*   cnt    = (int*)p;    p += (size_t)N_ * 4;
    int*   rowptr = (int*)p;    p += (size_t)(N_ + 1) * 4;
    int*   cursor = (int*)p;    p += (size_t)N_ * 4;
    int*   bsum   = (int*)p;    p += (size_t)nb * 4;
    int*   boff   = (int*)p;    p += (size_t)(nb + 1) * 4;

    hipMemsetAsync(packed, 0, (size_t)N_ * 8, stream);

    // L0 embeddings -> xA
    k_user_norm<<<(U_ + 3) / 4, 256, 0, stream>>>(user_w, xA, U_);
    k_item<<<(I_ + 3) / 4, 256, 0, stream>>>(audio, artist_w, album_w, proj_W,
                                             proj_b, artist_ids, album_ids,
                                             xA, I_, U_);

    // degree + counts (packed u64 atomics), then unpack
    k_deg_packed<<<(E_ + 255) / 256, 256, 0, stream>>>(ew, u_idx, i_idx,
                                                       packed, E_, U_);
    k_unpack<<<(N_ + 255) / 256, 256, 0, stream>>>(packed, dinv, cnt, N_);

    // CSR build
    k_scan1<<<nb, 1024, 0, stream>>>(cnt, rowptr, bsum, N_);
    k_scan2<<<1, 256, 0, stream>>>(bsum, boff, nb);
    k_scan3<<<(N_ + 1 + 255) / 256, 256, 0, stream>>>(rowptr, cursor, boff, N_, nb);
    k_fill<<<(E_ + 255) / 256, 256, 0, stream>>>(ew, u_idx, i_idx, dinv, cursor,
                                                 ents, E_, U_);

    // 3 layers, fused self-loop + running acc + epilogue
    const int ggrid = (N_ + 3) / 4;
    k_gather<<<ggrid, 256, 0, stream>>>(xA, xB, acc, dinv, rowptr, ents, N_, 0);
    k_gather<<<ggrid, 256, 0, stream>>>(xB, xA, acc, dinv, rowptr, ents, N_, 1);
    k_gather<<<ggrid, 256, 0, stream>>>(xA, xB, acc, dinv, rowptr, ents, N_, 2);
}

// Round 4
// 904.882 us; speedup vs baseline: 3.4010x; 1.6335x over previous
//
#include <hip/hip_runtime.h>
#include <hip/hip_fp16.h>
#include <math.h>

constexpr int D = 64;
constexpr int BROWS = 128;          // dst rows per bucket (bucket = dst >> 7)
constexpr int BCAP  = 6016;         // record capacity per bucket (avg item bucket 5120, +12 sigma)
constexpr int PASS1_CHUNK = 4096;   // edges per workgroup in pass 1
constexpr int NBMAX = 2048;

__device__ __forceinline__ float wave_reduce_sum(float v) {
    #pragma unroll
    for (int m = 1; m < 64; m <<= 1)
        v += __shfl_xor(v, m, 64);
    return v;
}

__device__ __forceinline__ float4 h4_to_f4(uint2 h) {
    __half2 a = *reinterpret_cast<__half2*>(&h.x);
    __half2 b = *reinterpret_cast<__half2*>(&h.y);
    float2 fa = __half22float2(a), fb = __half22float2(b);
    return make_float4(fa.x, fa.y, fb.x, fb.y);
}

__device__ __forceinline__ uint2 f4_to_h4(float4 f) {
    __half2 a = __floats2half2_rn(f.x, f.y);
    __half2 b = __floats2half2_rn(f.z, f.w);
    uint2 r;
    r.x = *reinterpret_cast<unsigned*>(&a);
    r.y = *reinterpret_cast<unsigned*>(&b);
    return r;
}

// ---- L0: user embeddings = l2norm(user_w) -> x0 fp16, wave per row ----
__global__ void k_user_norm(const float* __restrict__ user_w,
                            __half* __restrict__ x, int U_) {
    int wid  = (blockIdx.x * blockDim.x + threadIdx.x) >> 6;
    int lane = threadIdx.x & 63;
    if (wid >= U_) return;
    size_t o = (size_t)wid * D + lane;
    float v  = user_w[o];
    float ss = wave_reduce_sum(v * v);
    x[o] = __float2half(v / fmaxf(sqrtf(ss), 1e-12f));
}

// ---- L0: item embeddings = l2norm([audio, artist+album] @ W^T + b) ----
__global__ void __launch_bounds__(256) k_item(
        const float* __restrict__ audio,
        const float* __restrict__ artist_w, const float* __restrict__ album_w,
        const float* __restrict__ proj_W,   const float* __restrict__ proj_b,
        const int* __restrict__ artist_ids, const int* __restrict__ album_ids,
        __half* __restrict__ x, int I_, int U_) {
    __shared__ float Wt[128 * 64];   // 32 KiB, transposed: Wt[k*64+d]
    for (int idx = threadIdx.x; idx < 128 * 64; idx += 256) {
        int d = idx >> 7, k = idx & 127;
        Wt[k * 64 + d] = proj_W[idx];
    }
    __syncthreads();

    int lane = threadIdx.x & 63;
    int item = __builtin_amdgcn_readfirstlane(
                   (int)((blockIdx.x * blockDim.x + threadIdx.x) >> 6));
    if (item >= I_) return;              // wave-uniform

    int aid = artist_ids[item];
    int bid = album_ids[item];
    float fa = audio[(size_t)item * D + lane];
    float fm = artist_w[(size_t)aid * D + lane] + album_w[(size_t)bid * D + lane];

    float acc = proj_b[lane];
    #pragma unroll 8
    for (int k = 0; k < 64; ++k)
        acc = fmaf(__shfl(fa, k, 64), Wt[k * 64 + lane], acc);
    #pragma unroll 8
    for (int k = 0; k < 64; ++k)
        acc = fmaf(__shfl(fm, k, 64), Wt[(64 + k) * 64 + lane], acc);

    float ss = wave_reduce_sum(acc * acc);
    x[(size_t)(U_ + item) * D + lane] = __float2half(acc / fmaxf(sqrtf(ss), 1e-12f));
}

// ---- pass 1: scatter records (dst_local|dir|e) into coarse buckets ----
// LDS-aggregated cursors: ~0.6M global atomics instead of 8M.
__global__ void __launch_bounds__(256) k_scatter1(
        const int* __restrict__ u_idx, const int* __restrict__ i_idx,
        unsigned* __restrict__ records, int* __restrict__ gCursor,
        int E_, int U_, int NB) {
    __shared__ int hist[NBMAX];
    __shared__ int base[NBMAX];
    const int tid = threadIdx.x;
    const int e0 = blockIdx.x * PASS1_CHUNK;
    int uu[16], vv[16];
    for (int b = tid; b < NB; b += 256) hist[b] = 0;
    __syncthreads();
    #pragma unroll
    for (int j = 0; j < 16; ++j) {
        int e = e0 + j * 256 + tid;
        uu[j] = -1;
        if (e < E_) {
            int u = u_idx[e];
            int v = U_ + i_idx[e];
            uu[j] = u; vv[j] = v;
            atomicAdd(&hist[u >> 7], 1);
            atomicAdd(&hist[v >> 7], 1);
        }
    }
    __syncthreads();
    for (int b = tid; b < NB; b += 256) {
        int c = hist[b];
        base[b] = c ? atomicAdd(&gCursor[b], c) : 0;
        hist[b] = 0;                      // reuse as local cursor
    }
    __syncthreads();
    #pragma unroll
    for (int j = 0; j < 16; ++j) {
        if (uu[j] >= 0) {
            unsigned e = (unsigned)(e0 + j * 256 + tid);
            int u = uu[j], v = vv[j];
            int bu = u >> 7, bv = v >> 7;
            int offu = base[bu] + atomicAdd(&hist[bu], 1);
            if (offu < BCAP)   // dir=0: dst=u, src=U+i
                records[(size_t)bu * BCAP + offu] =
                    ((unsigned)(u & 127) << 22) | e;
            int offv = base[bv] + atomicAdd(&hist[bv], 1);
            if (offv < BCAP)   // dir=1: dst=U+i, src=u
                records[(size_t)bv * BCAP + offv] =
                    ((unsigned)(v & 127) << 22) | (1u << 21) | e;
        }
    }
}

// ---- exclusive scan over bucket counts (single block) ----
__global__ void __launch_bounds__(1024) k_bscan(const int* __restrict__ gCursor,
                                                int* __restrict__ bucketBase,
                                                int NB) {
    __shared__ int s[1024];
    int t = threadIdx.x;
    int e0 = (2 * t     < NB) ? min(gCursor[2 * t], BCAP)     : 0;
    int e1 = (2 * t + 1 < NB) ? min(gCursor[2 * t + 1], BCAP) : 0;
    int x = e0 + e1;
    s[t] = x; __syncthreads();
    for (int off = 1; off < 1024; off <<= 1) {
        int v = (t >= off) ? s[t - off] : 0;
        __syncthreads();
        s[t] += v;
        __syncthreads();
    }
    int excl = s[t] - x;
    if (2 * t     < NB) bucketBase[2 * t]     = excl;
    if (2 * t + 1 < NB) bucketBase[2 * t + 1] = excl + e0;
}

// ---- pass 2: per bucket, LDS counting-sort -> dense ents + rowptr + dinv,
//      plus fused yA scale (y0 = dinv * x0) ----
__global__ void __launch_bounds__(256) k_build(
        const unsigned* __restrict__ records, const int* __restrict__ gCursor,
        const int* __restrict__ bucketBase,
        const int* __restrict__ u_idx, const int* __restrict__ i_idx,
        const float* __restrict__ ew,
        int2* __restrict__ ents, int* __restrict__ rowptr,
        float* __restrict__ dinv, __half2* __restrict__ yA,
        int N_, int U_, int NB) {
    __shared__ int   s_cnt[BROWS];
    __shared__ int   s_cur[BROWS];
    __shared__ float s_w[BROWS];
    const int b   = blockIdx.x;
    const int tid = threadIdx.x;
    const unsigned* rec = records + (size_t)b * BCAP;
    const int R     = min(gCursor[b], BCAP);
    const int gbase = bucketBase[b];
    if (tid < BROWS) { s_cnt[tid] = 0; s_w[tid] = 0.0f; }
    __syncthreads();
    // A: per-row counts
    for (int r = tid; r < R; r += 256)
        atomicAdd(&s_cnt[rec[r] >> 22], 1);
    __syncthreads();
    // B: exclusive scan over 128 rows -> rowptr, cursors
    int own = (tid < BROWS) ? s_cnt[tid] : 0;
    for (int off = 1; off < BROWS; off <<= 1) {
        int v = (tid >= off && tid < BROWS) ? s_cnt[tid - off] : 0;
        __syncthreads();
        if (tid < BROWS) s_cnt[tid] += v;
        __syncthreads();
    }
    if (tid < BROWS) {
        int excl = s_cnt[tid] - own;
        s_cur[tid] = excl;
        int gid = b * BROWS + tid;
        if (gid < N_) rowptr[gid] = gbase + excl;
    }
    if (b == NB - 1 && tid == 0) rowptr[N_] = gbase + R;
    __syncthreads();
    // C: place entries (batch-8 software pipeline for the scattered reads)
    for (int r0 = 0; r0 < R; r0 += 256 * 8) {
        unsigned rc[8]; int s1[8], s2[8]; float wv[8];
        #pragma unroll
        for (int j = 0; j < 8; ++j) {
            int r = r0 + j * 256 + tid;
            rc[j] = (r < R) ? rec[r] : 0xFFFFFFFFu;
        }
        #pragma unroll
        for (int j = 0; j < 8; ++j) {
            if (rc[j] != 0xFFFFFFFFu) {
                int e = (int)(rc[j] & 0x1FFFFFu);
                s1[j] = u_idx[e];
                s2[j] = i_idx[e];
                wv[j] = ew[e];
            }
        }
        #pragma unroll
        for (int j = 0; j < 8; ++j) {
            if (rc[j] != 0xFFFFFFFFu) {
                int dl  = (int)(rc[j] >> 22);
                int dir = (int)((rc[j] >> 21) & 1u);
                int src = dir ? s1[j] : (U_ + s2[j]);
                float w = fmaxf(wv[j], 1e-6f);
                int pos = gbase + atomicAdd(&s_cur[dl], 1);
                ents[pos] = make_int2(src, __float_as_int(w));
                atomicAdd(&s_w[dl], w);
            }
        }
    }
    __syncthreads();
    // D: dinv = rsqrt(wsum + 1)
    if (tid < BROWS) {
        int gid = b * BROWS + tid;
        if (gid < N_) {
            float di = 1.0f / sqrtf(s_w[tid] + 1.0f);
            dinv[gid] = di;
            s_w[tid] = di;
        }
    }
    __syncthreads();
    // E: scale this bucket's yA rows: y0 = dinv * x0
    for (int t = tid; t < BROWS * 32; t += 256) {
        int r = t >> 5, cc = t & 31;
        int gid = b * BROWS + r;
        if (gid < N_) {
            float di = s_w[r];
            size_t o = (size_t)gid * 32 + cc;
            float2 f = __half22float2(yA[o]);
            yA[o] = __floats2half2_rn(f.x * di, f.y * di);
        }
    }
}

// ---- propagation layer in y-domain: s = y[dst] + sum w*y[src];
//      y_next = dinv^2 * s.  Quarter-wave: 4 edges/step, half4 per lane.
// mode 0: write yn = y1; ysum = y0 + y1
// mode 1: write yn = y2; ysum += y2
// mode 2: out = l2norm(ysum + y3)        (yn unused)
__global__ void __launch_bounds__(256) k_gather(
        const uint2* __restrict__ ys, uint2* __restrict__ yn,
        uint2* __restrict__ ysum, float4* __restrict__ outp,
        const float* __restrict__ dinv, const int* __restrict__ rowptr,
        const int2* __restrict__ ents, int N_, int mode) {
    const int lane = threadIdx.x & 63;
    const int q = lane >> 4;             // quarter 0..3
    const int c = lane & 15;             // half4 index within row
    const int wid = __builtin_amdgcn_readfirstlane(
                        (int)((blockIdx.x * blockDim.x + threadIdx.x) >> 6));
    if (wid >= N_) return;
    const size_t rowoff = (size_t)wid * 16 + c;
    const int beg = rowptr[wid], end = rowptr[wid + 1];
    float4 a = make_float4(0.f, 0.f, 0.f, 0.f);
    for (int j0 = beg; j0 < end; j0 += 64) {
        int m = end - j0; if (m > 64) m = 64;
        int2 rec = make_int2(0, 0);
        if (lane < m) rec = ents[j0 + lane];   // coalesced 512 B
        int kmax = (m + 3) >> 2;
        #pragma unroll 4
        for (int k = 0; k < kmax; ++k) {
            int idx = 4 * k + q;               // quarter-interleaved edges
            int src   = __shfl(rec.x, idx, 64);
            float w   = __int_as_float(__shfl(rec.y, idx, 64));
            if (idx < m) {
                float4 v = h4_to_f4(ys[(size_t)src * 16 + c]);
                a.x = fmaf(w, v.x, a.x);
                a.y = fmaf(w, v.y, a.y);
                a.z = fmaf(w, v.z, a.z);
                a.w = fmaf(w, v.w, a.w);
            }
        }
    }
    // combine the 4 quarter partial sums (lanes l, l^16, l^32, l^48 share c)
    a.x += __shfl_xor(a.x, 16, 64); a.y += __shfl_xor(a.y, 16, 64);
    a.z += __shfl_xor(a.z, 16, 64); a.w += __shfl_xor(a.w, 16, 64);
    a.x += __shfl_xor(a.x, 32, 64); a.y += __shfl_xor(a.y, 32, 64);
    a.z += __shfl_xor(a.z, 32, 64); a.w += __shfl_xor(a.w, 32, 64);

    float4 yold = h4_to_f4(ys[rowoff]);        // self-loop term
    float di = dinv[wid], d2 = di * di;
    float4 yn4 = make_float4(d2 * (a.x + yold.x), d2 * (a.y + yold.y),
                             d2 * (a.z + yold.z), d2 * (a.w + yold.w));
    if (mode == 2) {
        if (q == 0) {
            float4 vs = h4_to_f4(ysum[rowoff]);
            float4 v = make_float4(vs.x + yn4.x, vs.y + yn4.y,
                                   vs.z + yn4.z, vs.w + yn4.w);
            float ss = v.x * v.x + v.y * v.y + v.z * v.z + v.w * v.w;
            #pragma unroll
            for (int mm = 1; mm < 16; mm <<= 1)
                ss += __shfl_xor(ss, mm, 64);  // partners stay within quarter 0
            float inv = 1.0f / fmaxf(sqrtf(ss), 1e-12f);
            outp[rowoff] = make_float4(v.x * inv, v.y * inv, v.z * inv, v.w * inv);
        }
    } else {
        if (q == 0) yn[rowoff] = f4_to_h4(yn4);
        if (q == 1) {
            float4 t;
            if (mode == 0)
                t = make_float4(yold.x + yn4.x, yold.y + yn4.y,
                                yold.z + yn4.z, yold.w + yn4.w);
            else {
                float4 vs = h4_to_f4(ysum[rowoff]);
                t = make_float4(vs.x + yn4.x, vs.y + yn4.y,
                                vs.z + yn4.z, vs.w + yn4.w);
            }
            ysum[rowoff] = f4_to_h4(t);
        }
    }
}

extern "C" void kernel_launch(void* const* d_in, const int* in_sizes, int n_in,
                              void* d_out, int out_size, void* d_ws, size_t ws_size,
                              hipStream_t stream) {
    const float* user_w     = (const float*)d_in[0];
    const float* audio      = (const float*)d_in[1];
    const float* artist_w   = (const float*)d_in[2];
    const float* album_w    = (const float*)d_in[3];
    const float* proj_W     = (const float*)d_in[4];
    const float* proj_b     = (const float*)d_in[5];
    const float* ew         = (const float*)d_in[6];
    const int*   u_idx      = (const int*)d_in[7];
    const int*   i_idx      = (const int*)d_in[8];
    const int*   artist_ids = (const int*)d_in[9];
    const int*   album_ids  = (const int*)d_in[10];

    const int U_ = in_sizes[0] / D;
    const int I_ = in_sizes[1] / D;
    const int E_ = in_sizes[6];
    const int N_ = U_ + I_;
    const int NB = (N_ + BROWS - 1) / BROWS;    // 1172

    size_t xbytes = (size_t)N_ * D * sizeof(__half);      // 19.2 MB
    size_t recbytes = (size_t)NB * BCAP * sizeof(unsigned);
    size_t rreg = 2 * xbytes > recbytes ? 2 * xbytes : recbytes;

    char* p = (char*)d_ws;
    __half* yA = (__half*)p;            p += xbytes;
    char* R = p;                        p += rreg;
    __half* yB   = (__half*)R;                           // aliases records
    __half* ysum = (__half*)(R + xbytes);                // (records dead by then)
    unsigned* records = (unsigned*)R;
    int2*  ents   = (int2*)p;           p += (size_t)2 * E_ * sizeof(int2);
    int*   rowptr = (int*)p;            p += (size_t)(N_ + 1) * 4;
    float* dinv   = (float*)p;          p += (size_t)N_ * 4;
    int*   gCursor    = (int*)p;        p += (size_t)NB * 4;
    int*   bucketBase = (int*)p;        p += (size_t)NB * 4;

    hipMemsetAsync(gCursor, 0, (size_t)NB * 4, stream);

    // L0 embeddings -> yA (holds x0 until k_build scales it to y0)
    k_user_norm<<<(U_ + 3) / 4, 256, 0, stream>>>(user_w, yA, U_);
    k_item<<<(I_ + 3) / 4, 256, 0, stream>>>(audio, artist_w, album_w, proj_W,
                                             proj_b, artist_ids, album_ids,
                                             yA, I_, U_);

    // adjacency build: bucket scatter -> scan -> counting sort (+ y scale)
    k_scatter1<<<(E_ + PASS1_CHUNK - 1) / PASS1_CHUNK, 256, 0, stream>>>(
        u_idx, i_idx, records, gCursor, E_, U_, NB);
    k_bscan<<<1, 1024, 0, stream>>>(gCursor, bucketBase, NB);
    k_build<<<NB, 256, 0, stream>>>(records, gCursor, bucketBase, u_idx, i_idx,
                                    ew, ents, rowptr, dinv, (__half2*)yA,
                                    N_, U_, NB);

    // 3 layers in y-domain; out = l2norm(y0+y1+y2+y3)
    const int ggrid = (N_ + 3) / 4;
    k_gather<<<ggrid, 256, 0, stream>>>((uint2*)yA, (uint2*)yB, (uint2*)ysum,
                                        (float4*)d_out, dinv, rowptr, ents, N_, 0);
    k_gather<<<ggrid, 256, 0, stream>>>((uint2*)yB, (uint2*)yA, (uint2*)ysum,
                                        (float4*)d_out, dinv, rowptr, ents, N_, 1);
    k_gather<<<ggrid, 256, 0, stream>>>((uint2*)yA, (uint2*)yB, (uint2*)ysum,
                                        (float4*)d_out, dinv, rowptr, ents, N_, 2);
}

// Round 5
// 753.908 us; speedup vs baseline: 4.0821x; 1.2003x over previous
//
#include <hip/hip_runtime.h>
#include <hip/hip_fp16.h>
#include <math.h>

constexpr int D = 64;
constexpr int WPAD = 65;            // Wt leading-dim pad: banks stride 1 on write
constexpr int BROWS = 128;          // dst rows per bucket (bucket = dst >> 7)
constexpr int BCAP  = 6016;         // record capacity per bucket
constexpr int PASS1_CHUNK = 4096;   // edges per workgroup in pass 1
constexpr int NBMAX = 2048;

__device__ __forceinline__ float wave_reduce_sum(float v) {
    #pragma unroll
    for (int m = 1; m < 64; m <<= 1)
        v += __shfl_xor(v, m, 64);
    return v;
}

__device__ __forceinline__ float4 h4_to_f4(uint2 h) {
    __half2 a = *reinterpret_cast<__half2*>(&h.x);
    __half2 b = *reinterpret_cast<__half2*>(&h.y);
    float2 fa = __half22float2(a), fb = __half22float2(b);
    return make_float4(fa.x, fa.y, fb.x, fb.y);
}

__device__ __forceinline__ uint2 f4_to_h4(float4 f) {
    __half2 a = __floats2half2_rn(f.x, f.y);
    __half2 b = __floats2half2_rn(f.z, f.w);
    uint2 r;
    r.x = *reinterpret_cast<unsigned*>(&a);
    r.y = *reinterpret_cast<unsigned*>(&b);
    return r;
}

// ---- L0: user embeddings = l2norm(user_w) -> x0 fp16, wave per row ----
__global__ void k_user_norm(const float* __restrict__ user_w,
                            __half* __restrict__ x, int U_) {
    int wid  = (blockIdx.x * blockDim.x + threadIdx.x) >> 6;
    int lane = threadIdx.x & 63;
    if (wid >= U_) return;
    size_t o = (size_t)wid * D + lane;
    float v  = user_w[o];
    float ss = wave_reduce_sum(v * v);
    x[o] = __float2half(v / fmaxf(sqrtf(ss), 1e-12f));
}

// ---- L0: item embeddings = l2norm([audio, artist+album] @ W^T + b) ----
// Wt padded to leading dim 65: write banks stride 1 (conflict-free),
// read Wt[k*65+lane] -> (k+lane)%32 -> 2-way (free).
__global__ void __launch_bounds__(256) k_item(
        const float* __restrict__ audio,
        const float* __restrict__ artist_w, const float* __restrict__ album_w,
        const float* __restrict__ proj_W,   const float* __restrict__ proj_b,
        const int* __restrict__ artist_ids, const int* __restrict__ album_ids,
        __half* __restrict__ x, int I_, int U_) {
    __shared__ float Wt[128 * WPAD];   // 33.3 KiB, transposed: Wt[k*WPAD+d]
    for (int idx = threadIdx.x; idx < 128 * 64; idx += 256) {
        int d = idx >> 7, k = idx & 127;
        Wt[k * WPAD + d] = proj_W[idx];
    }
    __syncthreads();

    int lane = threadIdx.x & 63;
    int item = __builtin_amdgcn_readfirstlane(
                   (int)((blockIdx.x * blockDim.x + threadIdx.x) >> 6));
    if (item >= I_) return;              // wave-uniform

    int aid = artist_ids[item];
    int bid = album_ids[item];
    float fa = audio[(size_t)item * D + lane];
    float fm = artist_w[(size_t)aid * D + lane] + album_w[(size_t)bid * D + lane];

    float acc = proj_b[lane];
    #pragma unroll 8
    for (int k = 0; k < 64; ++k)
        acc = fmaf(__shfl(fa, k, 64), Wt[k * WPAD + lane], acc);
    #pragma unroll 8
    for (int k = 0; k < 64; ++k)
        acc = fmaf(__shfl(fm, k, 64), Wt[(64 + k) * WPAD + lane], acc);

    float ss = wave_reduce_sum(acc * acc);
    x[(size_t)(U_ + item) * D + lane] = __float2half(acc / fmaxf(sqrtf(ss), 1e-12f));
}

// ---- pass 1: scatter records (dst_local|dir|e) into coarse buckets ----
__global__ void __launch_bounds__(256) k_scatter1(
        const int* __restrict__ u_idx, const int* __restrict__ i_idx,
        unsigned* __restrict__ records, int* __restrict__ gCursor,
        int E_, int U_, int NB) {
    __shared__ int hist[NBMAX];
    __shared__ int base[NBMAX];
    const int tid = threadIdx.x;
    const int e0 = blockIdx.x * PASS1_CHUNK;
    int uu[16], vv[16];
    for (int b = tid; b < NB; b += 256) hist[b] = 0;
    __syncthreads();
    #pragma unroll
    for (int j = 0; j < 16; ++j) {
        int e = e0 + j * 256 + tid;
        uu[j] = -1;
        if (e < E_) {
            int u = u_idx[e];
            int v = U_ + i_idx[e];
            uu[j] = u; vv[j] = v;
            atomicAdd(&hist[u >> 7], 1);
            atomicAdd(&hist[v >> 7], 1);
        }
    }
    __syncthreads();
    for (int b = tid; b < NB; b += 256) {
        int c = hist[b];
        base[b] = c ? atomicAdd(&gCursor[b], c) : 0;
        hist[b] = 0;                      // reuse as local cursor
    }
    __syncthreads();
    #pragma unroll
    for (int j = 0; j < 16; ++j) {
        if (uu[j] >= 0) {
            unsigned e = (unsigned)(e0 + j * 256 + tid);
            int u = uu[j], v = vv[j];
            int bu = u >> 7, bv = v >> 7;
            int offu = base[bu] + atomicAdd(&hist[bu], 1);
            if (offu < BCAP)   // dir=0: dst=u, src=U+i
                records[(size_t)bu * BCAP + offu] =
                    ((unsigned)(u & 127) << 22) | e;
            int offv = base[bv] + atomicAdd(&hist[bv], 1);
            if (offv < BCAP)   // dir=1: dst=U+i, src=u
                records[(size_t)bv * BCAP + offv] =
                    ((unsigned)(v & 127) << 22) | (1u << 21) | e;
        }
    }
}

// ---- exclusive scan over bucket counts (single block) ----
__global__ void __launch_bounds__(1024) k_bscan(const int* __restrict__ gCursor,
                                                int* __restrict__ bucketBase,
                                                int NB) {
    __shared__ int s[1024];
    int t = threadIdx.x;
    int e0 = (2 * t     < NB) ? min(gCursor[2 * t], BCAP)     : 0;
    int e1 = (2 * t + 1 < NB) ? min(gCursor[2 * t + 1], BCAP) : 0;
    int x = e0 + e1;
    s[t] = x; __syncthreads();
    for (int off = 1; off < 1024; off <<= 1) {
        int v = (t >= off) ? s[t - off] : 0;
        __syncthreads();
        s[t] += v;
        __syncthreads();
    }
    int excl = s[t] - x;
    if (2 * t     < NB) bucketBase[2 * t]     = excl;
    if (2 * t + 1 < NB) bucketBase[2 * t + 1] = excl + e0;
}

// ---- pass 2: per bucket, LDS counting-sort -> dense ents + rowptr + dinv,
//      plus fused yA scale (y0 = dinv * x0) ----
__global__ void __launch_bounds__(256) k_build(
        const unsigned* __restrict__ records, const int* __restrict__ gCursor,
        const int* __restrict__ bucketBase,
        const int* __restrict__ u_idx, const int* __restrict__ i_idx,
        const float* __restrict__ ew,
        int2* __restrict__ ents, int* __restrict__ rowptr,
        float* __restrict__ dinv, __half2* __restrict__ yA,
        int N_, int U_, int NB) {
    __shared__ int   s_cnt[BROWS];
    __shared__ int   s_cur[BROWS];
    __shared__ float s_w[BROWS];
    const int b   = blockIdx.x;
    const int tid = threadIdx.x;
    const unsigned* rec = records + (size_t)b * BCAP;
    const int R     = min(gCursor[b], BCAP);
    const int gbase = bucketBase[b];
    if (tid < BROWS) { s_cnt[tid] = 0; s_w[tid] = 0.0f; }
    __syncthreads();
    // A: per-row counts
    for (int r = tid; r < R; r += 256)
        atomicAdd(&s_cnt[rec[r] >> 22], 1);
    __syncthreads();
    // B: exclusive scan over 128 rows -> rowptr, cursors
    int own = (tid < BROWS) ? s_cnt[tid] : 0;
    for (int off = 1; off < BROWS; off <<= 1) {
        int v = (tid >= off && tid < BROWS) ? s_cnt[tid - off] : 0;
        __syncthreads();
        if (tid < BROWS) s_cnt[tid] += v;
        __syncthreads();
    }
    if (tid < BROWS) {
        int excl = s_cnt[tid] - own;
        s_cur[tid] = excl;
        int gid = b * BROWS + tid;
        if (gid < N_) rowptr[gid] = gbase + excl;
    }
    if (b == NB - 1 && tid == 0) rowptr[N_] = gbase + R;
    __syncthreads();
    // C: place entries (batch-8 software pipeline for the scattered reads)
    for (int r0 = 0; r0 < R; r0 += 256 * 8) {
        unsigned rc[8]; int s1[8], s2[8]; float wv[8];
        #pragma unroll
        for (int j = 0; j < 8; ++j) {
            int r = r0 + j * 256 + tid;
            rc[j] = (r < R) ? rec[r] : 0xFFFFFFFFu;
        }
        #pragma unroll
        for (int j = 0; j < 8; ++j) {
            if (rc[j] != 0xFFFFFFFFu) {
                int e = (int)(rc[j] & 0x1FFFFFu);
                s1[j] = u_idx[e];
                s2[j] = i_idx[e];
                wv[j] = ew[e];
            }
        }
        #pragma unroll
        for (int j = 0; j < 8; ++j) {
            if (rc[j] != 0xFFFFFFFFu) {
                int dl  = (int)(rc[j] >> 22);
                int dir = (int)((rc[j] >> 21) & 1u);
                int src = dir ? s1[j] : (U_ + s2[j]);
                float w = fmaxf(wv[j], 1e-6f);
                int pos = gbase + atomicAdd(&s_cur[dl], 1);
                ents[pos] = make_int2(src, __float_as_int(w));
                atomicAdd(&s_w[dl], w);
            }
        }
    }
    __syncthreads();
    // D: dinv = rsqrt(wsum + 1)
    if (tid < BROWS) {
        int gid = b * BROWS + tid;
        if (gid < N_) {
            float di = 1.0f / sqrtf(s_w[tid] + 1.0f);
            dinv[gid] = di;
            s_w[tid] = di;
        }
    }
    __syncthreads();
    // E: scale this bucket's yA rows: y0 = dinv * x0
    for (int t = tid; t < BROWS * 32; t += 256) {
        int r = t >> 5, cc = t & 31;
        int gid = b * BROWS + r;
        if (gid < N_) {
            float di = s_w[r];
            size_t o = (size_t)gid * 32 + cc;
            float2 f = __half22float2(yA[o]);
            yA[o] = __floats2half2_rn(f.x * di, f.y * di);
        }
    }
}

// ---- propagation layer in y-domain: s = y[dst] + sum w*y[src];
//      y_next = dinv^2 * s.  Quarter-wave: 4 edges/step, half4 per lane.
// mode 0: write yn = y1; ysum = y0 + y1
// mode 1: write yn = y2; ysum += y2
// mode 2: out = l2norm(ysum + y3)        (yn unused)
__global__ void __launch_bounds__(256) k_gather(
        const uint2* __restrict__ ys, uint2* __restrict__ yn,
        uint2* __restrict__ ysum, float4* __restrict__ outp,
        const float* __restrict__ dinv, const int* __restrict__ rowptr,
        const int2* __restrict__ ents, int N_, int mode) {
    const int lane = threadIdx.x & 63;
    const int q = lane >> 4;             // quarter 0..3
    const int c = lane & 15;             // half4 index within row
    const int wid = __builtin_amdgcn_readfirstlane(
                        (int)((blockIdx.x * blockDim.x + threadIdx.x) >> 6));
    if (wid >= N_) return;
    const size_t rowoff = (size_t)wid * 16 + c;
    const int beg = rowptr[wid], end = rowptr[wid + 1];
    float4 a = make_float4(0.f, 0.f, 0.f, 0.f);
    for (int j0 = beg; j0 < end; j0 += 64) {
        int m = end - j0; if (m > 64) m = 64;
        int2 rec = make_int2(0, 0);
        if (lane < m) rec = ents[j0 + lane];   // coalesced 512 B
        int kmax = (m + 3) >> 2;
        #pragma unroll 4
        for (int k = 0; k < kmax; ++k) {
            int idx = 4 * k + q;               // quarter-interleaved edges
            int src   = __shfl(rec.x, idx, 64);
            float w   = __int_as_float(__shfl(rec.y, idx, 64));
            if (idx < m) {
                float4 v = h4_to_f4(ys[(size_t)src * 16 + c]);
                a.x = fmaf(w, v.x, a.x);
                a.y = fmaf(w, v.y, a.y);
                a.z = fmaf(w, v.z, a.z);
                a.w = fmaf(w, v.w, a.w);
            }
        }
    }
    // combine the 4 quarter partial sums (lanes l, l^16, l^32, l^48 share c)
    a.x += __shfl_xor(a.x, 16, 64); a.y += __shfl_xor(a.y, 16, 64);
    a.z += __shfl_xor(a.z, 16, 64); a.w += __shfl_xor(a.w, 16, 64);
    a.x += __shfl_xor(a.x, 32, 64); a.y += __shfl_xor(a.y, 32, 64);
    a.z += __shfl_xor(a.z, 32, 64); a.w += __shfl_xor(a.w, 32, 64);

    float4 yold = h4_to_f4(ys[rowoff]);        // self-loop term
    float di = dinv[wid], d2 = di * di;
    float4 yn4 = make_float4(d2 * (a.x + yold.x), d2 * (a.y + yold.y),
                             d2 * (a.z + yold.z), d2 * (a.w + yold.w));
    if (mode == 2) {
        if (q == 0) {
            float4 vs = h4_to_f4(ysum[rowoff]);
            float4 v = make_float4(vs.x + yn4.x, vs.y + yn4.y,
                                   vs.z + yn4.z, vs.w + yn4.w);
            float ss = v.x * v.x + v.y * v.y + v.z * v.z + v.w * v.w;
            #pragma unroll
            for (int mm = 1; mm < 16; mm <<= 1)
                ss += __shfl_xor(ss, mm, 64);  // partners stay within quarter 0
            float inv = 1.0f / fmaxf(sqrtf(ss), 1e-12f);
            outp[rowoff] = make_float4(v.x * inv, v.y * inv, v.z * inv, v.w * inv);
        }
    } else {
        if (q == 0) yn[rowoff] = f4_to_h4(yn4);
        if (q == 1) {
            float4 t;
            if (mode == 0)
                t = make_float4(yold.x + yn4.x, yold.y + yn4.y,
                                yold.z + yn4.z, yold.w + yn4.w);
            else {
                float4 vs = h4_to_f4(ysum[rowoff]);
                t = make_float4(vs.x + yn4.x, vs.y + yn4.y,
                                vs.z + yn4.z, vs.w + yn4.w);
            }
            ysum[rowoff] = f4_to_h4(t);
        }
    }
}

extern "C" void kernel_launch(void* const* d_in, const int* in_sizes, int n_in,
                              void* d_out, int out_size, void* d_ws, size_t ws_size,
                              hipStream_t stream) {
    const float* user_w     = (const float*)d_in[0];
    const float* audio      = (const float*)d_in[1];
    const float* artist_w   = (const float*)d_in[2];
    const float* album_w    = (const float*)d_in[3];
    const float* proj_W     = (const float*)d_in[4];
    const float* proj_b     = (const float*)d_in[5];
    const float* ew         = (const float*)d_in[6];
    const int*   u_idx      = (const int*)d_in[7];
    const int*   i_idx      = (const int*)d_in[8];
    const int*   artist_ids = (const int*)d_in[9];
    const int*   album_ids  = (const int*)d_in[10];

    const int U_ = in_sizes[0] / D;
    const int I_ = in_sizes[1] / D;
    const int E_ = in_sizes[6];
    const int N_ = U_ + I_;
    const int NB = (N_ + BROWS - 1) / BROWS;    // 1172

    size_t xbytes = (size_t)N_ * D * sizeof(__half);      // 19.2 MB
    size_t recbytes = (size_t)NB * BCAP * sizeof(unsigned);
    size_t rreg = 2 * xbytes > recbytes ? 2 * xbytes : recbytes;

    char* p = (char*)d_ws;
    __half* yA = (__half*)p;            p += xbytes;
    char* R = p;                        p += rreg;
    __half* yB   = (__half*)R;                           // aliases records
    __half* ysum = (__half*)(R + xbytes);                // (records dead by then)
    unsigned* records = (unsigned*)R;
    int2*  ents   = (int2*)p;           p += (size_t)2 * E_ * sizeof(int2);
    int*   rowptr = (int*)p;            p += (size_t)(N_ + 1) * 4;
    float* dinv   = (float*)p;          p += (size_t)N_ * 4;
    int*   gCursor    = (int*)p;        p += (size_t)NB * 4;
    int*   bucketBase = (int*)p;        p += (size_t)NB * 4;

    hipMemsetAsync(gCursor, 0, (size_t)NB * 4, stream);

    // L0 embeddings -> yA (holds x0 until k_build scales it to y0)
    k_user_norm<<<(U_ + 3) / 4, 256, 0, stream>>>(user_w, yA, U_);
    k_item<<<(I_ + 3) / 4, 256, 0, stream>>>(audio, artist_w, album_w, proj_W,
                                             proj_b, artist_ids, album_ids,
                                             yA, I_, U_);

    // adjacency build: bucket scatter -> scan -> counting sort (+ y scale)
    k_scatter1<<<(E_ + PASS1_CHUNK - 1) / PASS1_CHUNK, 256, 0, stream>>>(
        u_idx, i_idx, records, gCursor, E_, U_, NB);
    k_bscan<<<1, 1024, 0, stream>>>(gCursor, bucketBase, NB);
    k_build<<<NB, 256, 0, stream>>>(records, gCursor, bucketBase, u_idx, i_idx,
                                    ew, ents, rowptr, dinv, (__half2*)yA,
                                    N_, U_, NB);

    // 3 layers in y-domain; out = l2norm(y0+y1+y2+y3)
    const int ggrid = (N_ + 3) / 4;
    k_gather<<<ggrid, 256, 0, stream>>>((uint2*)yA, (uint2*)yB, (uint2*)ysum,
                                        (float4*)d_out, dinv, rowptr, ents, N_, 0);
    k_gather<<<ggrid, 256, 0, stream>>>((uint2*)yB, (uint2*)yA, (uint2*)ysum,
                                        (float4*)d_out, dinv, rowptr, ents, N_, 1);
    k_gather<<<ggrid, 256, 0, stream>>>((uint2*)yA, (uint2*)yB, (uint2*)ysum,
                                        (float4*)d_out, dinv, rowptr, ents, N_, 2);
}

// Round 6
// 634.027 us; speedup vs baseline: 4.8539x; 1.1891x over previous
//
#include <hip/hip_runtime.h>
#include <hip/hip_fp16.h>
#include <math.h>

constexpr int D = 64;
constexpr int WPAD = 65;            // Wt leading-dim pad: banks stride 1 on write
constexpr int BROWS = 128;          // dst rows per bucket (bucket = dst >> 7)
constexpr int BCAP  = 6016;         // record capacity per bucket
constexpr int PASS1_CHUNK = 4096;   // edges per workgroup in pass 1
constexpr int NBMAX = 2048;

__device__ __forceinline__ float wave_reduce_sum(float v) {
    #pragma unroll
    for (int m = 1; m < 64; m <<= 1)
        v += __shfl_xor(v, m, 64);
    return v;
}

__device__ __forceinline__ float4 h4_to_f4(uint2 h) {
    __half2 a = *reinterpret_cast<__half2*>(&h.x);
    __half2 b = *reinterpret_cast<__half2*>(&h.y);
    float2 fa = __half22float2(a), fb = __half22float2(b);
    return make_float4(fa.x, fa.y, fb.x, fb.y);
}

__device__ __forceinline__ uint2 f4_to_h4(float4 f) {
    __half2 a = __floats2half2_rn(f.x, f.y);
    __half2 b = __floats2half2_rn(f.z, f.w);
    uint2 r;
    r.x = *reinterpret_cast<unsigned*>(&a);
    r.y = *reinterpret_cast<unsigned*>(&b);
    return r;
}

// ---- L0: user embeddings = l2norm(user_w) -> x0 fp16, wave per row ----
__global__ void k_user_norm(const float* __restrict__ user_w,
                            __half* __restrict__ x, int U_) {
    int wid  = (blockIdx.x * blockDim.x + threadIdx.x) >> 6;
    int lane = threadIdx.x & 63;
    if (wid >= U_) return;
    size_t o = (size_t)wid * D + lane;
    float v  = user_w[o];
    float ss = wave_reduce_sum(v * v);
    x[o] = __float2half(v / fmaxf(sqrtf(ss), 1e-12f));
}

// ---- L0: item embeddings = l2norm([audio, artist+album] @ W^T + b) ----
__global__ void __launch_bounds__(256) k_item(
        const float* __restrict__ audio,
        const float* __restrict__ artist_w, const float* __restrict__ album_w,
        const float* __restrict__ proj_W,   const float* __restrict__ proj_b,
        const int* __restrict__ artist_ids, const int* __restrict__ album_ids,
        __half* __restrict__ x, int I_, int U_) {
    __shared__ float Wt[128 * WPAD];   // transposed + padded: Wt[k*WPAD+d]
    for (int idx = threadIdx.x; idx < 128 * 64; idx += 256) {
        int d = idx >> 7, k = idx & 127;
        Wt[k * WPAD + d] = proj_W[idx];
    }
    __syncthreads();

    int lane = threadIdx.x & 63;
    int item = __builtin_amdgcn_readfirstlane(
                   (int)((blockIdx.x * blockDim.x + threadIdx.x) >> 6));
    if (item >= I_) return;              // wave-uniform

    int aid = artist_ids[item];
    int bid = album_ids[item];
    float fa = audio[(size_t)item * D + lane];
    float fm = artist_w[(size_t)aid * D + lane] + album_w[(size_t)bid * D + lane];

    float acc = proj_b[lane];
    #pragma unroll 8
    for (int k = 0; k < 64; ++k)
        acc = fmaf(__shfl(fa, k, 64), Wt[k * WPAD + lane], acc);
    #pragma unroll 8
    for (int k = 0; k < 64; ++k)
        acc = fmaf(__shfl(fm, k, 64), Wt[(64 + k) * WPAD + lane], acc);

    float ss = wave_reduce_sum(acc * acc);
    x[(size_t)(U_ + item) * D + lane] = __float2half(acc / fmaxf(sqrtf(ss), 1e-12f));
}

// ---- pass 1: scatter FAT records (dst_local|src, weight) into buckets ----
// Edge arrays read coalesced HERE so pass 2 never gathers them.
__global__ void __launch_bounds__(256) k_scatter1(
        const int* __restrict__ u_idx, const int* __restrict__ i_idx,
        const float* __restrict__ ew,
        uint2* __restrict__ records, int* __restrict__ gCursor,
        int E_, int U_, int NB) {
    __shared__ int hist[NBMAX];
    __shared__ int base[NBMAX];
    const int tid = threadIdx.x;
    const int e0 = blockIdx.x * PASS1_CHUNK;
    int uu[16], vv[16]; unsigned wb[16];
    for (int b = tid; b < NB; b += 256) hist[b] = 0;
    __syncthreads();
    #pragma unroll
    for (int j = 0; j < 16; ++j) {
        int e = e0 + j * 256 + tid;
        uu[j] = -1;
        if (e < E_) {
            int u = u_idx[e];
            int v = U_ + i_idx[e];
            float w = fmaxf(ew[e], 1e-6f);
            uu[j] = u; vv[j] = v; wb[j] = __float_as_uint(w);
            atomicAdd(&hist[u >> 7], 1);
            atomicAdd(&hist[v >> 7], 1);
        }
    }
    __syncthreads();
    for (int b = tid; b < NB; b += 256) {
        int c = hist[b];
        base[b] = c ? atomicAdd(&gCursor[b], c) : 0;
        hist[b] = 0;                      // reuse as local cursor
    }
    __syncthreads();
    #pragma unroll
    for (int j = 0; j < 16; ++j) {
        if (uu[j] >= 0) {
            int u = uu[j], v = vv[j];
            int bu = u >> 7, bv = v >> 7;
            int offu = base[bu] + atomicAdd(&hist[bu], 1);
            if (offu < BCAP)   // dst=u, src=v(item node)
                records[(size_t)bu * BCAP + offu] =
                    make_uint2(((unsigned)(u & 127) << 18) | (unsigned)v, wb[j]);
            int offv = base[bv] + atomicAdd(&hist[bv], 1);
            if (offv < BCAP)   // dst=v, src=u
                records[(size_t)bv * BCAP + offv] =
                    make_uint2(((unsigned)(v & 127) << 18) | (unsigned)u, wb[j]);
        }
    }
}

// ---- exclusive scan over bucket counts (single block) ----
__global__ void __launch_bounds__(1024) k_bscan(const int* __restrict__ gCursor,
                                                int* __restrict__ bucketBase,
                                                int NB) {
    __shared__ int s[1024];
    int t = threadIdx.x;
    int e0 = (2 * t     < NB) ? min(gCursor[2 * t], BCAP)     : 0;
    int e1 = (2 * t + 1 < NB) ? min(gCursor[2 * t + 1], BCAP) : 0;
    int x = e0 + e1;
    s[t] = x; __syncthreads();
    for (int off = 1; off < 1024; off <<= 1) {
        int v = (t >= off) ? s[t - off] : 0;
        __syncthreads();
        s[t] += v;
        __syncthreads();
    }
    int excl = s[t] - x;
    if (2 * t     < NB) bucketBase[2 * t]     = excl;
    if (2 * t + 1 < NB) bucketBase[2 * t + 1] = excl + e0;
}

// ---- pass 2: per bucket, LDS counting-sort of fat records -> dense ents +
//      rowptr + dinv, plus fused yA scale (y0 = dinv * x0). Streams only. ----
__global__ void __launch_bounds__(256) k_build(
        const uint2* __restrict__ records, const int* __restrict__ gCursor,
        const int* __restrict__ bucketBase,
        int2* __restrict__ ents, int* __restrict__ rowptr,
        float* __restrict__ dinv, __half2* __restrict__ yA,
        int N_, int NB) {
    __shared__ int   s_cnt[BROWS];
    __shared__ int   s_cur[BROWS];
    __shared__ float s_w[BROWS];
    const int b   = blockIdx.x;
    const int tid = threadIdx.x;
    const uint2* rec = records + (size_t)b * BCAP;
    const int R     = min(gCursor[b], BCAP);
    const int gbase = bucketBase[b];
    if (tid < BROWS) { s_cnt[tid] = 0; s_w[tid] = 0.0f; }
    __syncthreads();
    // A: per-row counts
    for (int r = tid; r < R; r += 256)
        atomicAdd(&s_cnt[(rec[r].x >> 18) & 127], 1);
    __syncthreads();
    // B: exclusive scan over 128 rows -> rowptr, cursors
    int own = (tid < BROWS) ? s_cnt[tid] : 0;
    for (int off = 1; off < BROWS; off <<= 1) {
        int v = (tid >= off && tid < BROWS) ? s_cnt[tid - off] : 0;
        __syncthreads();
        if (tid < BROWS) s_cnt[tid] += v;
        __syncthreads();
    }
    if (tid < BROWS) {
        int excl = s_cnt[tid] - own;
        s_cur[tid] = excl;
        int gid = b * BROWS + tid;
        if (gid < N_) rowptr[gid] = gbase + excl;
    }
    if (b == NB - 1 && tid == 0) rowptr[N_] = gbase + R;
    __syncthreads();
    // C: place entries — record already holds (src, w); no gathers
    for (int r0 = 0; r0 < R; r0 += 256 * 8) {
        uint2 rc[8];
        #pragma unroll
        for (int j = 0; j < 8; ++j) {
            int r = r0 + j * 256 + tid;
            rc[j] = (r < R) ? rec[r] : make_uint2(0xFFFFFFFFu, 0);
        }
        #pragma unroll
        for (int j = 0; j < 8; ++j) {
            if (rc[j].x != 0xFFFFFFFFu) {
                int dl  = (int)((rc[j].x >> 18) & 127);
                int src = (int)(rc[j].x & 0x3FFFFu);
                float w = __uint_as_float(rc[j].y);
                int pos = gbase + atomicAdd(&s_cur[dl], 1);
                ents[pos] = make_int2(src, (int)rc[j].y);
                atomicAdd(&s_w[dl], w);
            }
        }
    }
    __syncthreads();
    // D: dinv = rsqrt(wsum + 1)
    if (tid < BROWS) {
        int gid = b * BROWS + tid;
        if (gid < N_) {
            float di = 1.0f / sqrtf(s_w[tid] + 1.0f);
            dinv[gid] = di;
            s_w[tid] = di;
        }
    }
    __syncthreads();
    // E: scale this bucket's yA rows: y0 = dinv * x0
    for (int t = tid; t < BROWS * 32; t += 256) {
        int r = t >> 5, cc = t & 31;
        int gid = b * BROWS + r;
        if (gid < N_) {
            float di = s_w[r];
            size_t o = (size_t)gid * 32 + cc;
            float2 f = __half22float2(yA[o]);
            yA[o] = __floats2half2_rn(f.x * di, f.y * di);
        }
    }
}

// ---- propagation layer in y-domain: s = y[dst] + sum w*y[src];
//      y_next = dinv^2 * s.  Quarter-wave: 4 edges/step, half4 per lane.
// mode 0: write yn = y1; ysum = y0 + y1
// mode 1: write yn = y2; ysum += y2
// mode 2: out = l2norm(ysum + y3)        (yn unused)
__global__ void __launch_bounds__(256) k_gather(
        const uint2* __restrict__ ys, uint2* __restrict__ yn,
        uint2* __restrict__ ysum, float4* __restrict__ outp,
        const float* __restrict__ dinv, const int* __restrict__ rowptr,
        const int2* __restrict__ ents, int N_, int mode) {
    const int lane = threadIdx.x & 63;
    const int q = lane >> 4;             // quarter 0..3
    const int c = lane & 15;             // half4 index within row
    const int wid = __builtin_amdgcn_readfirstlane(
                        (int)((blockIdx.x * blockDim.x + threadIdx.x) >> 6));
    if (wid >= N_) return;
    const size_t rowoff = (size_t)wid * 16 + c;
    const int beg = rowptr[wid], end = rowptr[wid + 1];
    float4 a = make_float4(0.f, 0.f, 0.f, 0.f);
    for (int j0 = beg; j0 < end; j0 += 64) {
        int m = end - j0; if (m > 64) m = 64;
        int2 rec = make_int2(0, 0);
        if (lane < m) rec = ents[j0 + lane];   // coalesced 512 B
        int kmax = (m + 3) >> 2;
        #pragma unroll 4
        for (int k = 0; k < kmax; ++k) {
            int idx = 4 * k + q;               // quarter-interleaved edges
            int src   = __shfl(rec.x, idx, 64);
            float w   = __int_as_float(__shfl(rec.y, idx, 64));
            if (idx < m) {
                float4 v = h4_to_f4(ys[(size_t)src * 16 + c]);
                a.x = fmaf(w, v.x, a.x);
                a.y = fmaf(w, v.y, a.y);
                a.z = fmaf(w, v.z, a.z);
                a.w = fmaf(w, v.w, a.w);
            }
        }
    }
    // combine the 4 quarter partial sums (lanes l, l^16, l^32, l^48 share c)
    a.x += __shfl_xor(a.x, 16, 64); a.y += __shfl_xor(a.y, 16, 64);
    a.z += __shfl_xor(a.z, 16, 64); a.w += __shfl_xor(a.w, 16, 64);
    a.x += __shfl_xor(a.x, 32, 64); a.y += __shfl_xor(a.y, 32, 64);
    a.z += __shfl_xor(a.z, 32, 64); a.w += __shfl_xor(a.w, 32, 64);

    float4 yold = h4_to_f4(ys[rowoff]);        // self-loop term
    float di = dinv[wid], d2 = di * di;
    float4 yn4 = make_float4(d2 * (a.x + yold.x), d2 * (a.y + yold.y),
                             d2 * (a.z + yold.z), d2 * (a.w + yold.w));
    if (mode == 2) {
        if (q == 0) {
            float4 vs = h4_to_f4(ysum[rowoff]);
            float4 v = make_float4(vs.x + yn4.x, vs.y + yn4.y,
                                   vs.z + yn4.z, vs.w + yn4.w);
            float ss = v.x * v.x + v.y * v.y + v.z * v.z + v.w * v.w;
            #pragma unroll
            for (int mm = 1; mm < 16; mm <<= 1)
                ss += __shfl_xor(ss, mm, 64);  // partners stay within quarter 0
            float inv = 1.0f / fmaxf(sqrtf(ss), 1e-12f);
            outp[rowoff] = make_float4(v.x * inv, v.y * inv, v.z * inv, v.w * inv);
        }
    } else {
        if (q == 0) yn[rowoff] = f4_to_h4(yn4);
        if (q == 1) {
            float4 t;
            if (mode == 0)
                t = make_float4(yold.x + yn4.x, yold.y + yn4.y,
                                yold.z + yn4.z, yold.w + yn4.w);
            else {
                float4 vs = h4_to_f4(ysum[rowoff]);
                t = make_float4(vs.x + yn4.x, vs.y + yn4.y,
                                vs.z + yn4.z, vs.w + yn4.w);
            }
            ysum[rowoff] = f4_to_h4(t);
        }
    }
}

extern "C" void kernel_launch(void* const* d_in, const int* in_sizes, int n_in,
                              void* d_out, int out_size, void* d_ws, size_t ws_size,
                              hipStream_t stream) {
    const float* user_w     = (const float*)d_in[0];
    const float* audio      = (const float*)d_in[1];
    const float* artist_w   = (const float*)d_in[2];
    const float* album_w    = (const float*)d_in[3];
    const float* proj_W     = (const float*)d_in[4];
    const float* proj_b     = (const float*)d_in[5];
    const float* ew         = (const float*)d_in[6];
    const int*   u_idx      = (const int*)d_in[7];
    const int*   i_idx      = (const int*)d_in[8];
    const int*   artist_ids = (const int*)d_in[9];
    const int*   album_ids  = (const int*)d_in[10];

    const int U_ = in_sizes[0] / D;
    const int I_ = in_sizes[1] / D;
    const int E_ = in_sizes[6];
    const int N_ = U_ + I_;
    const int NB = (N_ + BROWS - 1) / BROWS;    // 1172

    size_t xbytes = (size_t)N_ * D * sizeof(__half);      // 19.2 MB
    size_t recbytes = (size_t)NB * BCAP * sizeof(uint2);  // 56.4 MB
    size_t rreg = 2 * xbytes > recbytes ? 2 * xbytes : recbytes;

    char* p = (char*)d_ws;
    __half* yA = (__half*)p;            p += xbytes;
    char* R = p;                        p += rreg;
    __half* yB   = (__half*)R;                           // aliases records
    __half* ysum = (__half*)(R + xbytes);                // (records dead by then)
    uint2* records = (uint2*)R;
    int2*  ents   = (int2*)p;           p += (size_t)2 * E_ * sizeof(int2);
    int*   rowptr = (int*)p;            p += (size_t)(N_ + 1) * 4;
    float* dinv   = (float*)p;          p += (size_t)N_ * 4;
    int*   gCursor    = (int*)p;        p += (size_t)NB * 4;
    int*   bucketBase = (int*)p;        p += (size_t)NB * 4;

    hipMemsetAsync(gCursor, 0, (size_t)NB * 4, stream);

    // L0 embeddings -> yA (holds x0 until k_build scales it to y0)
    k_user_norm<<<(U_ + 3) / 4, 256, 0, stream>>>(user_w, yA, U_);
    k_item<<<(I_ + 3) / 4, 256, 0, stream>>>(audio, artist_w, album_w, proj_W,
                                             proj_b, artist_ids, album_ids,
                                             yA, I_, U_);

    // adjacency build: fat-record scatter -> scan -> counting sort (+ y scale)
    k_scatter1<<<(E_ + PASS1_CHUNK - 1) / PASS1_CHUNK, 256, 0, stream>>>(
        u_idx, i_idx, ew, records, gCursor, E_, U_, NB);
    k_bscan<<<1, 1024, 0, stream>>>(gCursor, bucketBase, NB);
    k_build<<<NB, 256, 0, stream>>>(records, gCursor, bucketBase,
                                    ents, rowptr, dinv, (__half2*)yA, N_, NB);

    // 3 layers in y-domain; out = l2norm(y0+y1+y2+y3)
    const int ggrid = (N_ + 3) / 4;
    k_gather<<<ggrid, 256, 0, stream>>>((uint2*)yA, (uint2*)yB, (uint2*)ysum,
                                        (float4*)d_out, dinv, rowptr, ents, N_, 0);
    k_gather<<<ggrid, 256, 0, stream>>>((uint2*)yB, (uint2*)yA, (uint2*)ysum,
                                        (float4*)d_out, dinv, rowptr, ents, N_, 1);
    k_gather<<<ggrid, 256, 0, stream>>>((uint2*)yA, (uint2*)yB, (uint2*)ysum,
                                        (float4*)d_out, dinv, rowptr, ents, N_, 2);
}

// Round 7
// 558.821 us; speedup vs baseline: 5.5072x; 1.1346x over previous
//
#include <hip/hip_runtime.h>
#include <hip/hip_fp16.h>
#include <math.h>

constexpr int D = 64;
constexpr int BROWS = 128;          // dst rows per bucket (bucket = dst >> 7)
constexpr int BCAP  = 6016;         // record capacity per bucket
constexpr int PASS1_CHUNK = 4096;   // edges per workgroup in pass 1
constexpr int NBMAX = 2048;
constexpr int WROW = 136;           // fp16 LDS row stride (128 + 8 pad)

typedef _Float16 half8 __attribute__((ext_vector_type(8)));
typedef float    f32x4 __attribute__((ext_vector_type(4)));

__device__ __forceinline__ float wave_reduce_sum(float v) {
    #pragma unroll
    for (int m = 1; m < 64; m <<= 1)
        v += __shfl_xor(v, m, 64);
    return v;
}

__device__ __forceinline__ float4 h4_to_f4(uint2 h) {
    __half2 a = *reinterpret_cast<__half2*>(&h.x);
    __half2 b = *reinterpret_cast<__half2*>(&h.y);
    float2 fa = __half22float2(a), fb = __half22float2(b);
    return make_float4(fa.x, fa.y, fb.x, fb.y);
}

__device__ __forceinline__ uint2 f4_to_h4(float4 f) {
    __half2 a = __floats2half2_rn(f.x, f.y);
    __half2 b = __floats2half2_rn(f.z, f.w);
    uint2 r;
    r.x = *reinterpret_cast<unsigned*>(&a);
    r.y = *reinterpret_cast<unsigned*>(&b);
    return r;
}

// ---- L0: user embeddings = l2norm(user_w) -> x0 fp16, wave per row ----
__global__ void k_user_norm(const float* __restrict__ user_w,
                            __half* __restrict__ x, int U_) {
    int wid  = (blockIdx.x * blockDim.x + threadIdx.x) >> 6;
    int lane = threadIdx.x & 63;
    if (wid >= U_) return;
    size_t o = (size_t)wid * D + lane;
    float v  = user_w[o];
    float ss = wave_reduce_sum(v * v);
    x[o] = __float2half(v / fmaxf(sqrtf(ss), 1e-12f));
}

// ---- L0 item projection as MFMA GEMM: [64 items/block] x [128 k] x [64 d].
// Wave computes 16 items: 4 d-tiles x 4 K-chunks of v_mfma_f32_16x16x32_f16.
// A-frag: A[m=lane&15][k=quad*8+j]; C/D: col(d)=lane&15, row(item)=quad*4+reg.
__global__ void __launch_bounds__(256) k_item(
        const float* __restrict__ audio,
        const float* __restrict__ artist_w, const float* __restrict__ album_w,
        const float* __restrict__ proj_W,   const float* __restrict__ proj_b,
        const int* __restrict__ artist_ids, const int* __restrict__ album_ids,
        __half* __restrict__ x, int I_, int U_) {
    __shared__ __align__(16) __half Wh[64 * WROW];      // proj_W in fp16
    __shared__ __align__(16) __half feat[4 * 16 * WROW]; // per-wave 16x128

    const int tid  = threadIdx.x;
    const int lane = tid & 63;
    const int wv   = tid >> 6;
    const int n    = lane & 15;       // d within tile / m within tile
    const int quad = lane >> 4;

    // stage W -> LDS fp16 (coalesced, conflict-free)
    for (int idx = tid; idx < 64 * 128; idx += 256) {
        int d = idx >> 7, k = idx & 127;
        Wh[d * WROW + k] = __float2half(proj_W[idx]);
    }
    __syncthreads();

    // B fragments (item-independent): B[n=d][k=c*32+quad*8+j], hoisted to regs
    half8 bfrag[4][4];
    #pragma unroll
    for (int dg = 0; dg < 4; ++dg)
        #pragma unroll
        for (int c = 0; c < 4; ++c)
            bfrag[dg][c] = *reinterpret_cast<const half8*>(
                &Wh[(dg * 16 + n) * WROW + c * 32 + quad * 8]);

    // stage this wave's 16 items' feat rows (fp32 gathers -> fp16 LDS)
    __half* fw = &feat[wv * 16 * WROW];
    const int itemBase = blockIdx.x * 64 + wv * 16;
    #pragma unroll 4
    for (int it = 0; it < 16; ++it) {
        int item = itemBase + it;
        float a = 0.f, m = 0.f;
        if (item < I_) {
            a = audio[(size_t)item * D + lane];
            int aid = artist_ids[item], bid = album_ids[item];
            m = artist_w[(size_t)aid * D + lane] +
                album_w[(size_t)bid * D + lane];
        }
        fw[it * WROW + lane]      = __float2half(a);
        fw[it * WROW + 64 + lane] = __float2half(m);
    }
    __syncthreads();   // uniform control flow; orders LDS writes vs frag reads

    // A fragments: A[m=n][k=c*32+quad*8+j]
    half8 afrag[4];
    #pragma unroll
    for (int c = 0; c < 4; ++c)
        afrag[c] = *reinterpret_cast<const half8*>(
            &fw[n * WROW + c * 32 + quad * 8]);

    f32x4 acc[4];
    #pragma unroll
    for (int dg = 0; dg < 4; ++dg) {
        f32x4 t = {0.f, 0.f, 0.f, 0.f};
        #pragma unroll
        for (int c = 0; c < 4; ++c)
            t = __builtin_amdgcn_mfma_f32_16x16x32_f16(afrag[c], bfrag[dg][c],
                                                       t, 0, 0, 0);
        acc[dg] = t;
    }

    // bias + l2norm per item (item = quad*4 + reg; 16 d-lanes per quad)
    float bias[4];
    #pragma unroll
    for (int dg = 0; dg < 4; ++dg) bias[dg] = proj_b[dg * 16 + n];

    float val[4][4], ss[4];
    #pragma unroll
    for (int r = 0; r < 4; ++r) {
        float s = 0.f;
        #pragma unroll
        for (int dg = 0; dg < 4; ++dg) {
            float v = acc[dg][r] + bias[dg];
            val[dg][r] = v;
            s = fmaf(v, v, s);
        }
        // reduce over the 16 lanes of this quad (xor<16 stays in quad)
        s += __shfl_xor(s, 1, 64);
        s += __shfl_xor(s, 2, 64);
        s += __shfl_xor(s, 4, 64);
        s += __shfl_xor(s, 8, 64);
        ss[r] = s;
    }

    #pragma unroll
    for (int r = 0; r < 4; ++r) {
        int item = itemBase + quad * 4 + r;
        if (item >= I_) continue;
        float inv = 1.0f / fmaxf(sqrtf(ss[r]), 1e-12f);
        size_t rowo = (size_t)(U_ + item) * D + n;
        #pragma unroll
        for (int dg = 0; dg < 4; ++dg)
            x[rowo + dg * 16] = __float2half(val[dg][r] * inv);
    }
}

// ---- pass 1: scatter FAT records (dst_local|src, weight) into buckets ----
__global__ void __launch_bounds__(256) k_scatter1(
        const int* __restrict__ u_idx, const int* __restrict__ i_idx,
        const float* __restrict__ ew,
        uint2* __restrict__ records, int* __restrict__ gCursor,
        int E_, int U_, int NB) {
    __shared__ int hist[NBMAX];
    __shared__ int base[NBMAX];
    const int tid = threadIdx.x;
    const int e0 = blockIdx.x * PASS1_CHUNK;
    int uu[16], vv[16]; unsigned wb[16];
    for (int b = tid; b < NB; b += 256) hist[b] = 0;
    __syncthreads();
    #pragma unroll
    for (int j = 0; j < 16; ++j) {
        int e = e0 + j * 256 + tid;
        uu[j] = -1;
        if (e < E_) {
            int u = u_idx[e];
            int v = U_ + i_idx[e];
            float w = fmaxf(ew[e], 1e-6f);
            uu[j] = u; vv[j] = v; wb[j] = __float_as_uint(w);
            atomicAdd(&hist[u >> 7], 1);
            atomicAdd(&hist[v >> 7], 1);
        }
    }
    __syncthreads();
    for (int b = tid; b < NB; b += 256) {
        int c = hist[b];
        base[b] = c ? atomicAdd(&gCursor[b], c) : 0;
        hist[b] = 0;                      // reuse as local cursor
    }
    __syncthreads();
    #pragma unroll
    for (int j = 0; j < 16; ++j) {
        if (uu[j] >= 0) {
            int u = uu[j], v = vv[j];
            int bu = u >> 7, bv = v >> 7;
            int offu = base[bu] + atomicAdd(&hist[bu], 1);
            if (offu < BCAP)   // dst=u, src=v(item node)
                records[(size_t)bu * BCAP + offu] =
                    make_uint2(((unsigned)(u & 127) << 18) | (unsigned)v, wb[j]);
            int offv = base[bv] + atomicAdd(&hist[bv], 1);
            if (offv < BCAP)   // dst=v, src=u
                records[(size_t)bv * BCAP + offv] =
                    make_uint2(((unsigned)(v & 127) << 18) | (unsigned)u, wb[j]);
        }
    }
}

// ---- exclusive scan over bucket counts (single block) ----
__global__ void __launch_bounds__(1024) k_bscan(const int* __restrict__ gCursor,
                                                int* __restrict__ bucketBase,
                                                int NB) {
    __shared__ int s[1024];
    int t = threadIdx.x;
    int e0 = (2 * t     < NB) ? min(gCursor[2 * t], BCAP)     : 0;
    int e1 = (2 * t + 1 < NB) ? min(gCursor[2 * t + 1], BCAP) : 0;
    int x = e0 + e1;
    s[t] = x; __syncthreads();
    for (int off = 1; off < 1024; off <<= 1) {
        int v = (t >= off) ? s[t - off] : 0;
        __syncthreads();
        s[t] += v;
        __syncthreads();
    }
    int excl = s[t] - x;
    if (2 * t     < NB) bucketBase[2 * t]     = excl;
    if (2 * t + 1 < NB) bucketBase[2 * t + 1] = excl + e0;
}

// ---- pass 2: per bucket, LDS counting-sort of fat records -> dense ents +
//      rowptr + dinv, plus fused yA scale (y0 = dinv * x0). Streams only. ----
__global__ void __launch_bounds__(256) k_build(
        const uint2* __restrict__ records, const int* __restrict__ gCursor,
        const int* __restrict__ bucketBase,
        int2* __restrict__ ents, int* __restrict__ rowptr,
        float* __restrict__ dinv, __half2* __restrict__ yA,
        int N_, int NB) {
    __shared__ int   s_cnt[BROWS];
    __shared__ int   s_cur[BROWS];
    __shared__ float s_w[BROWS];
    const int b   = blockIdx.x;
    const int tid = threadIdx.x;
    const uint2* rec = records + (size_t)b * BCAP;
    const int R     = min(gCursor[b], BCAP);
    const int gbase = bucketBase[b];
    if (tid < BROWS) { s_cnt[tid] = 0; s_w[tid] = 0.0f; }
    __syncthreads();
    // A: per-row counts
    for (int r = tid; r < R; r += 256)
        atomicAdd(&s_cnt[(rec[r].x >> 18) & 127], 1);
    __syncthreads();
    // B: exclusive scan over 128 rows -> rowptr, cursors
    int own = (tid < BROWS) ? s_cnt[tid] : 0;
    for (int off = 1; off < BROWS; off <<= 1) {
        int v = (tid >= off && tid < BROWS) ? s_cnt[tid - off] : 0;
        __syncthreads();
        if (tid < BROWS) s_cnt[tid] += v;
        __syncthreads();
    }
    if (tid < BROWS) {
        int excl = s_cnt[tid] - own;
        s_cur[tid] = excl;
        int gid = b * BROWS + tid;
        if (gid < N_) rowptr[gid] = gbase + excl;
    }
    if (b == NB - 1 && tid == 0) rowptr[N_] = gbase + R;
    __syncthreads();
    // C: place entries — record already holds (src, w); no gathers
    for (int r0 = 0; r0 < R; r0 += 256 * 8) {
        uint2 rc[8];
        #pragma unroll
        for (int j = 0; j < 8; ++j) {
            int r = r0 + j * 256 + tid;
            rc[j] = (r < R) ? rec[r] : make_uint2(0xFFFFFFFFu, 0);
        }
        #pragma unroll
        for (int j = 0; j < 8; ++j) {
            if (rc[j].x != 0xFFFFFFFFu) {
                int dl  = (int)((rc[j].x >> 18) & 127);
                int src = (int)(rc[j].x & 0x3FFFFu);
                float w = __uint_as_float(rc[j].y);
                int pos = gbase + atomicAdd(&s_cur[dl], 1);
                ents[pos] = make_int2(src, (int)rc[j].y);
                atomicAdd(&s_w[dl], w);
            }
        }
    }
    __syncthreads();
    // D: dinv = rsqrt(wsum + 1)
    if (tid < BROWS) {
        int gid = b * BROWS + tid;
        if (gid < N_) {
            float di = 1.0f / sqrtf(s_w[tid] + 1.0f);
            dinv[gid] = di;
            s_w[tid] = di;
        }
    }
    __syncthreads();
    // E: scale this bucket's yA rows: y0 = dinv * x0
    for (int t = tid; t < BROWS * 32; t += 256) {
        int r = t >> 5, cc = t & 31;
        int gid = b * BROWS + r;
        if (gid < N_) {
            float di = s_w[r];
            size_t o = (size_t)gid * 32 + cc;
            float2 f = __half22float2(yA[o]);
            yA[o] = __floats2half2_rn(f.x * di, f.y * di);
        }
    }
}

// ---- propagation layer in y-domain: s = y[dst] + sum w*y[src];
//      y_next = dinv^2 * s.  Quarter-wave: 4 edges/step, half4 per lane.
// mode 0: write yn = y1; ysum = y0 + y1
// mode 1: write yn = y2; ysum += y2
// mode 2: out = l2norm(ysum + y3)        (yn unused)
__global__ void __launch_bounds__(256) k_gather(
        const uint2* __restrict__ ys, uint2* __restrict__ yn,
        uint2* __restrict__ ysum, float4* __restrict__ outp,
        const float* __restrict__ dinv, const int* __restrict__ rowptr,
        const int2* __restrict__ ents, int N_, int mode) {
    const int lane = threadIdx.x & 63;
    const int q = lane >> 4;             // quarter 0..3
    const int c = lane & 15;             // half4 index within row
    const int wid = __builtin_amdgcn_readfirstlane(
                        (int)((blockIdx.x * blockDim.x + threadIdx.x) >> 6));
    if (wid >= N_) return;
    const size_t rowoff = (size_t)wid * 16 + c;
    const int beg = rowptr[wid], end = rowptr[wid + 1];
    float4 a = make_float4(0.f, 0.f, 0.f, 0.f);
    for (int j0 = beg; j0 < end; j0 += 64) {
        int m = end - j0; if (m > 64) m = 64;
        int2 rec = make_int2(0, 0);
        if (lane < m) rec = ents[j0 + lane];   // coalesced 512 B
        int kmax = (m + 3) >> 2;
        #pragma unroll 4
        for (int k = 0; k < kmax; ++k) {
            int idx = 4 * k + q;               // quarter-interleaved edges
            int src   = __shfl(rec.x, idx, 64);
            float w   = __int_as_float(__shfl(rec.y, idx, 64));
            if (idx < m) {
                float4 v = h4_to_f4(ys[(size_t)src * 16 + c]);
                a.x = fmaf(w, v.x, a.x);
                a.y = fmaf(w, v.y, a.y);
                a.z = fmaf(w, v.z, a.z);
                a.w = fmaf(w, v.w, a.w);
            }
        }
    }
    // combine the 4 quarter partial sums (lanes l, l^16, l^32, l^48 share c)
    a.x += __shfl_xor(a.x, 16, 64); a.y += __shfl_xor(a.y, 16, 64);
    a.z += __shfl_xor(a.z, 16, 64); a.w += __shfl_xor(a.w, 16, 64);
    a.x += __shfl_xor(a.x, 32, 64); a.y += __shfl_xor(a.y, 32, 64);
    a.z += __shfl_xor(a.z, 32, 64); a.w += __shfl_xor(a.w, 32, 64);

    float4 yold = h4_to_f4(ys[rowoff]);        // self-loop term
    float di = dinv[wid], d2 = di * di;
    float4 yn4 = make_float4(d2 * (a.x + yold.x), d2 * (a.y + yold.y),
                             d2 * (a.z + yold.z), d2 * (a.w + yold.w));
    if (mode == 2) {
        if (q == 0) {
            float4 vs = h4_to_f4(ysum[rowoff]);
            float4 v = make_float4(vs.x + yn4.x, vs.y + yn4.y,
                                   vs.z + yn4.z, vs.w + yn4.w);
            float ss = v.x * v.x + v.y * v.y + v.z * v.z + v.w * v.w;
            #pragma unroll
            for (int mm = 1; mm < 16; mm <<= 1)
                ss += __shfl_xor(ss, mm, 64);  // partners stay within quarter 0
            float inv = 1.0f / fmaxf(sqrtf(ss), 1e-12f);
            outp[rowoff] = make_float4(v.x * inv, v.y * inv, v.z * inv, v.w * inv);
        }
    } else {
        if (q == 0) yn[rowoff] = f4_to_h4(yn4);
        if (q == 1) {
            float4 t;
            if (mode == 0)
                t = make_float4(yold.x + yn4.x, yold.y + yn4.y,
                                yold.z + yn4.z, yold.w + yn4.w);
            else {
                float4 vs = h4_to_f4(ysum[rowoff]);
                t = make_float4(vs.x + yn4.x, vs.y + yn4.y,
                                vs.z + yn4.z, vs.w + yn4.w);
            }
            ysum[rowoff] = f4_to_h4(t);
        }
    }
}

extern "C" void kernel_launch(void* const* d_in, const int* in_sizes, int n_in,
                              void* d_out, int out_size, void* d_ws, size_t ws_size,
                              hipStream_t stream) {
    const float* user_w     = (const float*)d_in[0];
    const float* audio      = (const float*)d_in[1];
    const float* artist_w   = (const float*)d_in[2];
    const float* album_w    = (const float*)d_in[3];
    const float* proj_W     = (const float*)d_in[4];
    const float* proj_b     = (const float*)d_in[5];
    const float* ew         = (const float*)d_in[6];
    const int*   u_idx      = (const int*)d_in[7];
    const int*   i_idx      = (const int*)d_in[8];
    const int*   artist_ids = (const int*)d_in[9];
    const int*   album_ids  = (const int*)d_in[10];

    const int U_ = in_sizes[0] / D;
    const int I_ = in_sizes[1] / D;
    const int E_ = in_sizes[6];
    const int N_ = U_ + I_;
    const int NB = (N_ + BROWS - 1) / BROWS;    // 1172

    size_t xbytes = (size_t)N_ * D * sizeof(__half);      // 19.2 MB
    size_t recbytes = (size_t)NB * BCAP * sizeof(uint2);  // 56.4 MB
    size_t rreg = 2 * xbytes > recbytes ? 2 * xbytes : recbytes;

    char* p = (char*)d_ws;
    __half* yA = (__half*)p;            p += xbytes;
    char* R = p;                        p += rreg;
    __half* yB   = (__half*)R;                           // aliases records
    __half* ysum = (__half*)(R + xbytes);                // (records dead by then)
    uint2* records = (uint2*)R;
    int2*  ents   = (int2*)p;           p += (size_t)2 * E_ * sizeof(int2);
    int*   rowptr = (int*)p;            p += (size_t)(N_ + 1) * 4;
    float* dinv   = (float*)p;          p += (size_t)N_ * 4;
    int*   gCursor    = (int*)p;        p += (size_t)NB * 4;
    int*   bucketBase = (int*)p;        p += (size_t)NB * 4;

    hipMemsetAsync(gCursor, 0, (size_t)NB * 4, stream);

    // L0 embeddings -> yA (holds x0 until k_build scales it to y0)
    k_user_norm<<<(U_ + 3) / 4, 256, 0, stream>>>(user_w, yA, U_);
    k_item<<<(I_ + 63) / 64, 256, 0, stream>>>(audio, artist_w, album_w, proj_W,
                                               proj_b, artist_ids, album_ids,
                                               yA, I_, U_);

    // adjacency build: fat-record scatter -> scan -> counting sort (+ y scale)
    k_scatter1<<<(E_ + PASS1_CHUNK - 1) / PASS1_CHUNK, 256, 0, stream>>>(
        u_idx, i_idx, ew, records, gCursor, E_, U_, NB);
    k_bscan<<<1, 1024, 0, stream>>>(gCursor, bucketBase, NB);
    k_build<<<NB, 256, 0, stream>>>(records, gCursor, bucketBase,
                                    ents, rowptr, dinv, (__half2*)yA, N_, NB);

    // 3 layers in y-domain; out = l2norm(y0+y1+y2+y3)
    const int ggrid = (N_ + 3) / 4;
    k_gather<<<ggrid, 256, 0, stream>>>((uint2*)yA, (uint2*)yB, (uint2*)ysum,
                                        (float4*)d_out, dinv, rowptr, ents, N_, 0);
    k_gather<<<ggrid, 256, 0, stream>>>((uint2*)yB, (uint2*)yA, (uint2*)ysum,
                                        (float4*)d_out, dinv, rowptr, ents, N_, 1);
    k_gather<<<ggrid, 256, 0, stream>>>((uint2*)yA, (uint2*)yB, (uint2*)ysum,
                                        (float4*)d_out, dinv, rowptr, ents, N_, 2);
}

// Round 8
// 492.680 us; speedup vs baseline: 6.2465x; 1.1342x over previous
//
#include <hip/hip_runtime.h>
#include <hip/hip_fp16.h>
#include <math.h>

constexpr int D = 64;
constexpr int BROWS = 128;          // dst rows per bucket (bucket = dst >> 7)
constexpr int BCAP  = 6016;         // record capacity per bucket
constexpr int PASS1_CHUNK = 4096;   // edges per workgroup in pass 1
constexpr int NBMAX = 2048;
constexpr int WROW = 136;           // fp16 LDS row stride (128 + 8 pad)

typedef _Float16 half8 __attribute__((ext_vector_type(8)));
typedef float    f32x4 __attribute__((ext_vector_type(4)));

__device__ __forceinline__ float wave_reduce_sum(float v) {
    #pragma unroll
    for (int m = 1; m < 64; m <<= 1)
        v += __shfl_xor(v, m, 64);
    return v;
}

__device__ __forceinline__ void h8_to_f8(uint4 h, float* f) {
    const __half2* hp = reinterpret_cast<const __half2*>(&h);
    #pragma unroll
    for (int i = 0; i < 4; ++i) {
        float2 t = __half22float2(hp[i]);
        f[2 * i] = t.x; f[2 * i + 1] = t.y;
    }
}

__device__ __forceinline__ uint4 f8_to_h8(const float* f) {
    uint4 r;
    unsigned* rp = &r.x;
    #pragma unroll
    for (int i = 0; i < 4; ++i) {
        __half2 h = __floats2half2_rn(f[2 * i], f[2 * i + 1]);
        rp[i] = *reinterpret_cast<unsigned*>(&h);
    }
    return r;
}

// ---- L0: user embeddings = l2norm(user_w) -> x0 fp16, wave per row ----
__global__ void k_user_norm(const float* __restrict__ user_w,
                            __half* __restrict__ x, int U_) {
    int wid  = (blockIdx.x * blockDim.x + threadIdx.x) >> 6;
    int lane = threadIdx.x & 63;
    if (wid >= U_) return;
    size_t o = (size_t)wid * D + lane;
    float v  = user_w[o];
    float ss = wave_reduce_sum(v * v);
    x[o] = __float2half(v / fmaxf(sqrtf(ss), 1e-12f));
}

// ---- L0 item projection as MFMA GEMM: [64 items/block] x [128 k] x [64 d].
__global__ void __launch_bounds__(256) k_item(
        const float* __restrict__ audio,
        const float* __restrict__ artist_w, const float* __restrict__ album_w,
        const float* __restrict__ proj_W,   const float* __restrict__ proj_b,
        const int* __restrict__ artist_ids, const int* __restrict__ album_ids,
        __half* __restrict__ x, int I_, int U_) {
    __shared__ __align__(16) __half Wh[64 * WROW];      // proj_W in fp16
    __shared__ __align__(16) __half feat[4 * 16 * WROW]; // per-wave 16x128

    const int tid  = threadIdx.x;
    const int lane = tid & 63;
    const int wv   = tid >> 6;
    const int n    = lane & 15;       // d within tile / m within tile
    const int quad = lane >> 4;

    for (int idx = tid; idx < 64 * 128; idx += 256) {
        int d = idx >> 7, k = idx & 127;
        Wh[d * WROW + k] = __float2half(proj_W[idx]);
    }
    __syncthreads();

    half8 bfrag[4][4];
    #pragma unroll
    for (int dg = 0; dg < 4; ++dg)
        #pragma unroll
        for (int c = 0; c < 4; ++c)
            bfrag[dg][c] = *reinterpret_cast<const half8*>(
                &Wh[(dg * 16 + n) * WROW + c * 32 + quad * 8]);

    __half* fw = &feat[wv * 16 * WROW];
    const int itemBase = blockIdx.x * 64 + wv * 16;
    #pragma unroll 4
    for (int it = 0; it < 16; ++it) {
        int item = itemBase + it;
        float a = 0.f, m = 0.f;
        if (item < I_) {
            a = audio[(size_t)item * D + lane];
            int aid = artist_ids[item], bid = album_ids[item];
            m = artist_w[(size_t)aid * D + lane] +
                album_w[(size_t)bid * D + lane];
        }
        fw[it * WROW + lane]      = __float2half(a);
        fw[it * WROW + 64 + lane] = __float2half(m);
    }
    __syncthreads();

    half8 afrag[4];
    #pragma unroll
    for (int c = 0; c < 4; ++c)
        afrag[c] = *reinterpret_cast<const half8*>(
            &fw[n * WROW + c * 32 + quad * 8]);

    f32x4 acc[4];
    #pragma unroll
    for (int dg = 0; dg < 4; ++dg) {
        f32x4 t = {0.f, 0.f, 0.f, 0.f};
        #pragma unroll
        for (int c = 0; c < 4; ++c)
            t = __builtin_amdgcn_mfma_f32_16x16x32_f16(afrag[c], bfrag[dg][c],
                                                       t, 0, 0, 0);
        acc[dg] = t;
    }

    float bias[4];
    #pragma unroll
    for (int dg = 0; dg < 4; ++dg) bias[dg] = proj_b[dg * 16 + n];

    float val[4][4], ss[4];
    #pragma unroll
    for (int r = 0; r < 4; ++r) {
        float s = 0.f;
        #pragma unroll
        for (int dg = 0; dg < 4; ++dg) {
            float v = acc[dg][r] + bias[dg];
            val[dg][r] = v;
            s = fmaf(v, v, s);
        }
        s += __shfl_xor(s, 1, 64);
        s += __shfl_xor(s, 2, 64);
        s += __shfl_xor(s, 4, 64);
        s += __shfl_xor(s, 8, 64);
        ss[r] = s;
    }

    #pragma unroll
    for (int r = 0; r < 4; ++r) {
        int item = itemBase + quad * 4 + r;
        if (item >= I_) continue;
        float inv = 1.0f / fmaxf(sqrtf(ss[r]), 1e-12f);
        size_t rowo = (size_t)(U_ + item) * D + n;
        #pragma unroll
        for (int dg = 0; dg < 4; ++dg)
            x[rowo + dg * 16] = __float2half(val[dg][r] * inv);
    }
}

// ---- pass 1: scatter FAT records (dst_local|src, weight) into buckets ----
__global__ void __launch_bounds__(256) k_scatter1(
        const int* __restrict__ u_idx, const int* __restrict__ i_idx,
        const float* __restrict__ ew,
        uint2* __restrict__ records, int* __restrict__ gCursor,
        int E_, int U_, int NB) {
    __shared__ int hist[NBMAX];
    __shared__ int base[NBMAX];
    const int tid = threadIdx.x;
    const int e0 = blockIdx.x * PASS1_CHUNK;
    int uu[16], vv[16]; unsigned wb[16];
    for (int b = tid; b < NB; b += 256) hist[b] = 0;
    __syncthreads();
    #pragma unroll
    for (int j = 0; j < 16; ++j) {
        int e = e0 + j * 256 + tid;
        uu[j] = -1;
        if (e < E_) {
            int u = u_idx[e];
            int v = U_ + i_idx[e];
            float w = fmaxf(ew[e], 1e-6f);
            uu[j] = u; vv[j] = v; wb[j] = __float_as_uint(w);
            atomicAdd(&hist[u >> 7], 1);
            atomicAdd(&hist[v >> 7], 1);
        }
    }
    __syncthreads();
    for (int b = tid; b < NB; b += 256) {
        int c = hist[b];
        base[b] = c ? atomicAdd(&gCursor[b], c) : 0;
        hist[b] = 0;                      // reuse as local cursor
    }
    __syncthreads();
    #pragma unroll
    for (int j = 0; j < 16; ++j) {
        if (uu[j] >= 0) {
            int u = uu[j], v = vv[j];
            int bu = u >> 7, bv = v >> 7;
            int offu = base[bu] + atomicAdd(&hist[bu], 1);
            if (offu < BCAP)   // dst=u, src=v(item node)
                records[(size_t)bu * BCAP + offu] =
                    make_uint2(((unsigned)(u & 127) << 18) | (unsigned)v, wb[j]);
            int offv = base[bv] + atomicAdd(&hist[bv], 1);
            if (offv < BCAP)   // dst=v, src=u
                records[(size_t)bv * BCAP + offv] =
                    make_uint2(((unsigned)(v & 127) << 18) | (unsigned)u, wb[j]);
        }
    }
}

// ---- exclusive scan over bucket counts (single block) ----
__global__ void __launch_bounds__(1024) k_bscan(const int* __restrict__ gCursor,
                                                int* __restrict__ bucketBase,
                                                int NB) {
    __shared__ int s[1024];
    int t = threadIdx.x;
    int e0 = (2 * t     < NB) ? min(gCursor[2 * t], BCAP)     : 0;
    int e1 = (2 * t + 1 < NB) ? min(gCursor[2 * t + 1], BCAP) : 0;
    int x = e0 + e1;
    s[t] = x; __syncthreads();
    for (int off = 1; off < 1024; off <<= 1) {
        int v = (t >= off) ? s[t - off] : 0;
        __syncthreads();
        s[t] += v;
        __syncthreads();
    }
    int excl = s[t] - x;
    if (2 * t     < NB) bucketBase[2 * t]     = excl;
    if (2 * t + 1 < NB) bucketBase[2 * t + 1] = excl + e0;
}

// ---- pass 2: per bucket, LDS counting-sort of fat records -> packed 4B ents
//      (wfix14<<18 | src18) + rowptr + dinv, plus fused yA scale. ----
__global__ void __launch_bounds__(256) k_build(
        const uint2* __restrict__ records, const int* __restrict__ gCursor,
        const int* __restrict__ bucketBase,
        unsigned* __restrict__ ents, int* __restrict__ rowptr,
        float* __restrict__ dinv, __half2* __restrict__ yA,
        int N_, int NB) {
    __shared__ int   s_cnt[BROWS];
    __shared__ int   s_cur[BROWS];
    __shared__ float s_w[BROWS];
    const int b   = blockIdx.x;
    const int tid = threadIdx.x;
    const uint2* rec = records + (size_t)b * BCAP;
    const int R     = min(gCursor[b], BCAP);
    const int gbase = bucketBase[b];
    if (tid < BROWS) { s_cnt[tid] = 0; s_w[tid] = 0.0f; }
    __syncthreads();
    // A: per-row counts
    for (int r = tid; r < R; r += 256)
        atomicAdd(&s_cnt[(rec[r].x >> 18) & 127], 1);
    __syncthreads();
    // B: exclusive scan over 128 rows -> rowptr, cursors
    int own = (tid < BROWS) ? s_cnt[tid] : 0;
    for (int off = 1; off < BROWS; off <<= 1) {
        int v = (tid >= off && tid < BROWS) ? s_cnt[tid - off] : 0;
        __syncthreads();
        if (tid < BROWS) s_cnt[tid] += v;
        __syncthreads();
    }
    if (tid < BROWS) {
        int excl = s_cnt[tid] - own;
        s_cur[tid] = excl;
        int gid = b * BROWS + tid;
        if (gid < N_) rowptr[gid] = gbase + excl;
    }
    if (b == NB - 1 && tid == 0) rowptr[N_] = gbase + R;
    __syncthreads();
    // C: place packed entries — record already holds (src, w); no gathers
    for (int r0 = 0; r0 < R; r0 += 256 * 8) {
        uint2 rc[8];
        #pragma unroll
        for (int j = 0; j < 8; ++j) {
            int r = r0 + j * 256 + tid;
            rc[j] = (r < R) ? rec[r] : make_uint2(0xFFFFFFFFu, 0);
        }
        #pragma unroll
        for (int j = 0; j < 8; ++j) {
            if (rc[j].x != 0xFFFFFFFFu) {
                int dl  = (int)((rc[j].x >> 18) & 127);
                unsigned src = rc[j].x & 0x3FFFFu;
                float w = __uint_as_float(rc[j].y);
                unsigned wfix = (unsigned)fminf(w * 16384.f + 0.5f, 16383.f);
                int pos = gbase + atomicAdd(&s_cur[dl], 1);
                ents[pos] = (wfix << 18) | src;
                atomicAdd(&s_w[dl], w);
            }
        }
    }
    __syncthreads();
    // D: dinv = rsqrt(wsum + 1)
    if (tid < BROWS) {
        int gid = b * BROWS + tid;
        if (gid < N_) {
            float di = 1.0f / sqrtf(s_w[tid] + 1.0f);
            dinv[gid] = di;
            s_w[tid] = di;
        }
    }
    __syncthreads();
    // E: scale this bucket's yA rows: y0 = dinv * x0
    for (int t = tid; t < BROWS * 32; t += 256) {
        int r = t >> 5, cc = t & 31;
        int gid = b * BROWS + r;
        if (gid < N_) {
            float di = s_w[r];
            size_t o = (size_t)gid * 32 + cc;
            float2 f = __half22float2(yA[o]);
            yA[o] = __floats2half2_rn(f.x * di, f.y * di);
        }
    }
}

// ---- propagation layer in y-domain: s = y[dst] + 2^-14 * sum wfix*y[src];
//      y_next = dinv^2 * s.  8-lane row groups, half8 (16 B) per lane:
//      8 edges in flight per wave k-iter (1 KB/instruction).
// mode 0: write yn = y1; ysum = y0 + y1
// mode 1: write yn = y2; ysum += y2
// mode 2: out = l2norm(ysum + y3)        (yn unused)
__global__ void __launch_bounds__(256) k_gather(
        const uint4* __restrict__ ys, uint4* __restrict__ yn,
        uint4* __restrict__ ysum, float4* __restrict__ outp,
        const float* __restrict__ dinv, const int* __restrict__ rowptr,
        const unsigned* __restrict__ ents, int N_, int mode) {
    const int lane = threadIdx.x & 63;
    const int g  = lane >> 3;            // edge group 0..7
    const int c8 = lane & 7;             // half8 index within row
    const int wid = __builtin_amdgcn_readfirstlane(
                        (int)((blockIdx.x * blockDim.x + threadIdx.x) >> 6));
    if (wid >= N_) return;
    const int beg = rowptr[wid], end = rowptr[wid + 1];
    float a[8] = {0.f, 0.f, 0.f, 0.f, 0.f, 0.f, 0.f, 0.f};
    for (int j0 = beg; j0 < end; j0 += 64) {
        int m = end - j0; if (m > 64) m = 64;
        unsigned ent = 0;
        if (lane < m) ent = ents[j0 + lane];   // coalesced 256 B
        int kmax = (m + 7) >> 3;
        #pragma unroll 4
        for (int k = 0; k < kmax; ++k) {
            int idx = 8 * k + g;
            unsigned e = (unsigned)__shfl((int)ent, idx, 64);
            if (idx < m) {
                float wf = (float)(e >> 18);
                int src  = (int)(e & 0x3FFFFu);
                uint4 h = ys[(size_t)src * 8 + c8];   // 128 B row / 8 lanes
                float v[8]; h8_to_f8(h, v);
                #pragma unroll
                for (int i = 0; i < 8; ++i)
                    a[i] = fmaf(wf, v[i], a[i]);
            }
        }
    }
    // reduce the 8 group partials (lanes sharing c8)
    #pragma unroll
    for (int i = 0; i < 8; ++i) {
        a[i] += __shfl_xor(a[i], 8, 64);
        a[i] += __shfl_xor(a[i], 16, 64);
        a[i] += __shfl_xor(a[i], 32, 64);
    }

    const size_t ro = (size_t)wid * 8 + c8;
    float yold[8]; h8_to_f8(ys[ro], yold);
    float di = dinv[wid], d2 = di * di;
    float fin[8];
    #pragma unroll
    for (int i = 0; i < 8; ++i)
        fin[i] = d2 * fmaf(a[i], 1.0f / 16384.0f, yold[i]);

    if (mode == 2) {
        float vs[8]; h8_to_f8(ysum[ro], vs);
        float vv[8], sq = 0.f;
        #pragma unroll
        for (int i = 0; i < 8; ++i) {
            vv[i] = vs[i] + fin[i];
            sq = fmaf(vv[i], vv[i], sq);
        }
        sq += __shfl_xor(sq, 1, 64);
        sq += __shfl_xor(sq, 2, 64);
        sq += __shfl_xor(sq, 4, 64);
        float inv = 1.0f / fmaxf(sqrtf(sq), 1e-12f);
        if (g == 0) {
            size_t ob = (size_t)wid * 16 + c8 * 2;
            outp[ob]     = make_float4(vv[0] * inv, vv[1] * inv,
                                       vv[2] * inv, vv[3] * inv);
            outp[ob + 1] = make_float4(vv[4] * inv, vv[5] * inv,
                                       vv[6] * inv, vv[7] * inv);
        }
    } else {
        if (g == 0) yn[ro] = f8_to_h8(fin);
        if (g == 1) {
            float t[8];
            if (mode == 0) {
                #pragma unroll
                for (int i = 0; i < 8; ++i) t[i] = yold[i] + fin[i];
            } else {
                float vs[8]; h8_to_f8(ysum[ro], vs);
                #pragma unroll
                for (int i = 0; i < 8; ++i) t[i] = vs[i] + fin[i];
            }
            ysum[ro] = f8_to_h8(t);
        }
    }
}

extern "C" void kernel_launch(void* const* d_in, const int* in_sizes, int n_in,
                              void* d_out, int out_size, void* d_ws, size_t ws_size,
                              hipStream_t stream) {
    const float* user_w     = (const float*)d_in[0];
    const float* audio      = (const float*)d_in[1];
    const float* artist_w   = (const float*)d_in[2];
    const float* album_w    = (const float*)d_in[3];
    const float* proj_W     = (const float*)d_in[4];
    const float* proj_b     = (const float*)d_in[5];
    const float* ew         = (const float*)d_in[6];
    const int*   u_idx      = (const int*)d_in[7];
    const int*   i_idx      = (const int*)d_in[8];
    const int*   artist_ids = (const int*)d_in[9];
    const int*   album_ids  = (const int*)d_in[10];

    const int U_ = in_sizes[0] / D;
    const int I_ = in_sizes[1] / D;
    const int E_ = in_sizes[6];
    const int N_ = U_ + I_;
    const int NB = (N_ + BROWS - 1) / BROWS;    // 1172

    size_t xbytes = (size_t)N_ * D * sizeof(__half);      // 19.2 MB
    size_t recbytes = (size_t)NB * BCAP * sizeof(uint2);  // 56.4 MB
    size_t rreg = 2 * xbytes > recbytes ? 2 * xbytes : recbytes;

    char* p = (char*)d_ws;
    __half* yA = (__half*)p;            p += xbytes;
    char* R = p;                        p += rreg;
    __half* yB   = (__half*)R;                           // aliases records
    __half* ysum = (__half*)(R + xbytes);                // (records dead by then)
    uint2* records = (uint2*)R;
    unsigned* ents = (unsigned*)p;      p += (size_t)2 * E_ * sizeof(unsigned);
    int*   rowptr = (int*)p;            p += (size_t)(N_ + 1) * 4;
    float* dinv   = (float*)p;          p += (size_t)N_ * 4;
    int*   gCursor    = (int*)p;        p += (size_t)NB * 4;
    int*   bucketBase = (int*)p;        p += (size_t)NB * 4;

    hipMemsetAsync(gCursor, 0, (size_t)NB * 4, stream);

    // L0 embeddings -> yA (holds x0 until k_build scales it to y0)
    k_user_norm<<<(U_ + 3) / 4, 256, 0, stream>>>(user_w, yA, U_);
    k_item<<<(I_ + 63) / 64, 256, 0, stream>>>(audio, artist_w, album_w, proj_W,
                                               proj_b, artist_ids, album_ids,
                                               yA, I_, U_);

    // adjacency build: fat-record scatter -> scan -> counting sort (+ y scale)
    k_scatter1<<<(E_ + PASS1_CHUNK - 1) / PASS1_CHUNK, 256, 0, stream>>>(
        u_idx, i_idx, ew, records, gCursor, E_, U_, NB);
    k_bscan<<<1, 1024, 0, stream>>>(gCursor, bucketBase, NB);
    k_build<<<NB, 256, 0, stream>>>(records, gCursor, bucketBase,
                                    ents, rowptr, dinv, (__half2*)yA, N_, NB);

    // 3 layers in y-domain; out = l2norm(y0+y1+y2+y3)
    const int ggrid = (N_ + 3) / 4;
    k_gather<<<ggrid, 256, 0, stream>>>((uint4*)yA, (uint4*)yB, (uint4*)ysum,
                                        (float4*)d_out, dinv, rowptr, ents, N_, 0);
    k_gather<<<ggrid, 256, 0, stream>>>((uint4*)yB, (uint4*)yA, (uint4*)ysum,
                                        (float4*)d_out, dinv, rowptr, ents, N_, 1);
    k_gather<<<ggrid, 256, 0, stream>>>((uint4*)yA, (uint4*)yB, (uint4*)ysum,
                                        (float4*)d_out, dinv, rowptr, ents, N_, 2);
}